// Round 21
// baseline (512.221 us; speedup 1.0000x reference)
//
#include <hip/hip_runtime.h>
#include <hip/hip_bf16.h>

#define NN 100000
#define NE 600000

typedef __bf16 bf16x8 __attribute__((ext_vector_type(8)));
typedef float  f32x4  __attribute__((ext_vector_type(4)));
typedef float  f32x16 __attribute__((ext_vector_type(16)));

__device__ __forceinline__ float dot4(float4 a, float4 b){
  return a.x*b.x + a.y*b.y + a.z*b.z + a.w*b.w;
}
// unpack 2 packed bf16 (low = even channel) to floats
__device__ __forceinline__ void bf2f(unsigned v, float& a, float& b){
  union { unsigned u; float f; } ua, ub;
  ua.u = v << 16;
  ub.u = v & 0xFFFF0000u;
  a = ua.f; b = ub.f;
}
__device__ __forceinline__ float4 bf4f(uint2 v){
  float4 r;
  bf2f(v.x, r.x, r.y);
  bf2f(v.y, r.z, r.w);
  return r;
}

// ---------------- CSR build (dst-grouped) ----------------
__global__ void count_edges(const int* __restrict__ dst, int* __restrict__ cnt){
  int e = blockIdx.x*256 + threadIdx.x;
  if (e < NE){
    unsigned d = (unsigned)dst[e];
    if (d < NN) atomicAdd(&cnt[d], 1);
  }
}

__global__ void scan1(const int* __restrict__ cnt, int* __restrict__ offs, int* __restrict__ bsum){
  __shared__ int sh[256];
  const int tid = threadIdx.x;
  const int base = blockIdx.x*2048 + tid*8;
  int pre[8]; int s = 0;
  #pragma unroll
  for (int j=0;j<8;j++){
    int idx = base + j;
    int v = (idx < NN) ? cnt[idx] : 0;
    pre[j] = s; s += v;
  }
  sh[tid] = s;
  __syncthreads();
  for (int d=1; d<256; d<<=1){
    int t = (tid >= d) ? sh[tid-d] : 0;
    __syncthreads();
    sh[tid] += t;
    __syncthreads();
  }
  int off = (tid > 0) ? sh[tid-1] : 0;
  #pragma unroll
  for (int j=0;j<8;j++){
    int idx = base + j;
    if (idx < NN) offs[idx] = off + pre[j];
  }
  if (tid == 255) bsum[blockIdx.x] = sh[255];
}

__global__ void scan2(int* __restrict__ bsum){
  if (threadIdx.x == 0){
    int s = 0;
    for (int i=0;i<49;i++){ int t = bsum[i]; bsum[i] = s; s += t; }
  }
}

__global__ void scan3(int* __restrict__ offs, const int* __restrict__ bsum, int* __restrict__ cursor){
  int i = blockIdx.x*256 + threadIdx.x;
  if (i < NN){
    int v = offs[i] + bsum[i>>11];
    offs[i] = v; cursor[i] = v;
  }
  if (i == 0) offs[NN] = NE;
}

__global__ void fill_csr(const int* __restrict__ src, const int* __restrict__ dst,
                         int* __restrict__ cursor, int* __restrict__ csrsrc){
  int e = blockIdx.x*256 + threadIdx.x;
  if (e < NE){
    unsigned d = (unsigned)dst[e];
    unsigned s = (unsigned)src[e];
    if (d < NN && s < NN){
      int p = atomicAdd(&cursor[d], 1);
      csrsrc[p] = (int)s;
    }
  }
}

// ---------------- weight repack: fp32 W[K][C] -> bf16 hi/lo MFMA fragments ----
// 16x16x32 layout (used by o1, o2): elem (f,j): W[ks*32+(lane>>4)*8+j][t*16+(lane&15)]
__global__ void repack_w(const float* __restrict__ w1, const float* __restrict__ w2,
                         __bf16* __restrict__ phi, __bf16* __restrict__ plo)
{
  int gid = blockIdx.x*256 + threadIdx.x;
  const float* W; int C; size_t obase; int rem;
  if (gid < 2048)      { W = w1; C = 128; obase = 0;     rem = gid; }
  else if (gid < 3072) { W = w2; C = 64;  obase = 16384; rem = gid - 2048; }
  else return;
  const int lane = rem & 63;
  const int tks  = rem >> 6;
  const int ks = tks & 3, t = tks >> 2;
  const int col = t*16 + (lane & 15);
  const int kb  = ks*32 + (lane >> 4)*8;
  const size_t o = obase + (size_t)rem*8;
  #pragma unroll
  for (int j=0;j<8;j++){
    float v = W[(size_t)(kb+j)*C + col];
    __bf16 hb = (__bf16)v;
    phi[o+j] = hb;
    plo[o+j] = (__bf16)(v - (float)hb);
  }
}

// 32x32x16 layout (used by GAT Wg, C=128): frag f=(t*8+ks)*64+lane, elem j:
// W[ks*16+(lane>>5)*8+j][t*32+(lane&31)]
__global__ void repack_w32(const float* __restrict__ Wg,
                           __bf16* __restrict__ phi, __bf16* __restrict__ plo)
{
  int gid = blockIdx.x*256 + threadIdx.x;
  if (gid >= 8192) return;
  const int layer = gid >> 11, rem = gid & 2047;
  const float* W = Wg + (size_t)layer*16384;
  const int lane = rem & 63;
  const int tks  = rem >> 6;           // 0..31
  const int ks = tks & 7, t = tks >> 3;
  const int col = t*32 + (lane & 31);
  const int kb  = ks*16 + (lane >> 5)*8;
  const size_t o = (size_t)layer*16384 + (size_t)rem*8;
  #pragma unroll
  for (int j=0;j<8;j++){
    float v = W[(size_t)(kb+j)*128 + col];
    __bf16 hb = (__bf16)v;
    phi[o+j] = hb;
    plo[o+j] = (__bf16)(v - (float)hb);
  }
}

// ---------------- input MLP: h = relu(LN(x@w_in+b_in)) ----------------
__global__ __launch_bounds__(256) void input_mlp(const float* __restrict__ x,
    const float* __restrict__ win, const float* __restrict__ b,
    const float* __restrict__ lnw, const float* __restrict__ lnb,
    float* __restrict__ h)
{
  const int tid = threadIdx.x;
  const int g = tid >> 5, l = tid & 31;
  const int n = blockIdx.x*8 + g;
  const float4* W4 = (const float4*)win;
  float xr[6];
  #pragma unroll
  for (int k=0;k<6;k++) xr[k] = x[n*6+k];
  float4 s = ((const float4*)b)[l];
  #pragma unroll
  for (int k=0;k<6;k++){
    float4 w = W4[k*32 + l];
    s.x = fmaf(xr[k], w.x, s.x);
    s.y = fmaf(xr[k], w.y, s.y);
    s.z = fmaf(xr[k], w.z, s.z);
    s.w = fmaf(xr[k], w.w, s.w);
  }
  float sum = s.x+s.y+s.z+s.w;
  float sq  = dot4(s,s);
  #pragma unroll
  for (int o=16;o>=1;o>>=1){ sum += __shfl_xor(sum,o); sq += __shfl_xor(sq,o); }
  float mean = sum*(1.f/128.f);
  float var  = sq*(1.f/128.f) - mean*mean;
  float rr = rsqrtf(var + 1e-5f);
  float4 lw = ((const float4*)lnw)[l];
  float4 lb = ((const float4*)lnb)[l];
  float4 y;
  y.x = fmaxf((s.x-mean)*rr*lw.x + lb.x, 0.f);
  y.y = fmaxf((s.y-mean)*rr*lw.y + lb.y, 0.f);
  y.z = fmaxf((s.z-mean)*rr*lw.z + lb.z, 0.f);
  y.w = fmaxf((s.w-mean)*rr*lw.w + lb.w, 0.f);
  ((float4*)(h + (size_t)n*128))[l] = y;
}

// ---------------- GAT GEMM, 32x32x16 MFMA: Yb = bf16(X@W), als/ald fused ----
// One wave = 32 rows x 128 cols: B read once per 32 rows (half the L2 line
// requests of the 16x16 tiling, which measured request-bound at ~51 us).
// acc = 4 tiles x f32x16 (64 VGPR), A transient per ks, no LDS.
// C/D: col=lane&31, row=(reg&3)+8*(reg>>2)+4*(lane>>5)  [HW-verified]
// A: row=lane&31, k=ks*16+(lane>>5)*8+j ; B symmetric (k-perm cancels).
__global__ __launch_bounds__(256) void gemm32_gat(const float* __restrict__ X,
    const __bf16* __restrict__ Bhi, const __bf16* __restrict__ Blo,
    const float* __restrict__ asrc, const float* __restrict__ adst,
    __bf16* __restrict__ Yb, float* __restrict__ als, float* __restrict__ ald)
{
  const int tid = threadIdx.x;
  const int wid = tid >> 6, lane = tid & 63;
  const int lm = lane & 31, lh = lane >> 5;
  const int m0 = blockIdx.x*128 + wid*32;

  f32x16 acc[4];
  #pragma unroll
  for (int t=0;t<4;t++){
    #pragma unroll
    for (int i=0;i<16;i++) acc[t][i] = 0.f;
  }

  int row = m0 + lm; if (row >= NN) row = NN-1;
  const float* Xr = X + (size_t)row*128 + lh*8;
  const bf16x8* B8h = (const bf16x8*)Bhi;
  const bf16x8* B8l = (const bf16x8*)Blo;

  #pragma unroll
  for (int ks=0; ks<8; ks++){
    float4 u0 = *(const float4*)(Xr + ks*16);
    float4 u1 = *(const float4*)(Xr + ks*16 + 4);
    float v[8] = {u0.x,u0.y,u0.z,u0.w,u1.x,u1.y,u1.z,u1.w};
    bf16x8 Ahi, Alo;
    #pragma unroll
    for (int j=0;j<8;j++){
      __bf16 hb = (__bf16)v[j];
      Ahi[j] = hb;
      Alo[j] = (__bf16)(v[j] - (float)hb);
    }
    bf16x8 bh[4];
    #pragma unroll
    for (int t=0;t<4;t++) bh[t] = B8h[(t*8+ks)*64 + lane];
    #pragma unroll
    for (int t=0;t<4;t++)
      acc[t] = __builtin_amdgcn_mfma_f32_32x32x16_bf16(Ahi, bh[t], acc[t], 0,0,0);
    #pragma unroll
    for (int t=0;t<4;t++)
      acc[t] = __builtin_amdgcn_mfma_f32_32x32x16_bf16(Alo, bh[t], acc[t], 0,0,0);
    #pragma unroll
    for (int t=0;t<4;t++){
      bf16x8 bl = B8l[(t*8+ks)*64 + lane];
      acc[t] = __builtin_amdgcn_mfma_f32_32x32x16_bf16(Ahi, bl, acc[t], 0,0,0);
    }
  }

  // epilogue: Yb store + per-head (16-col) attention logit reductions
  #pragma unroll
  for (int t=0;t<4;t++){
    float av = asrc[t*32 + lm];
    float dv = adst[t*32 + lm];
    const int hd = t*2 + (lm >> 4);
    #pragma unroll
    for (int i=0;i<16;i++){
      int r = (i&3) + 8*(i>>2) + 4*lh;
      int n = m0 + r;
      float a = acc[t][i];
      if (n < NN) Yb[(size_t)n*128 + t*32 + lm] = (__bf16)a;
      float ps = a*av, pd = a*dv;
      ps += __shfl_xor(ps,1); ps += __shfl_xor(ps,2);
      ps += __shfl_xor(ps,4); ps += __shfl_xor(ps,8);
      pd += __shfl_xor(pd,1); pd += __shfl_xor(pd,2);
      pd += __shfl_xor(pd,4); pd += __shfl_xor(pd,8);
      if ((lane & 15) == 0 && n < NN){
        als[n*8 + hd] = ps;
        ald[n*8 + hd] = pd;
      }
    }
  }
}

// ---------------- MFMA split-bf16 GEMM (16x16x32): o1 (LN+ReLU) / o2 (+OUTP) --
template<int C, bool DO_LN, bool DO_RELU, bool OUTP>
__global__ __launch_bounds__(256) void gemm_mfma(const float* __restrict__ X,
    const __bf16* __restrict__ Bhi, const __bf16* __restrict__ Blo,
    const float* __restrict__ bias,
    const float* __restrict__ lnw, const float* __restrict__ lnb,
    float* __restrict__ Y,
    const float* __restrict__ w3, const float* __restrict__ b3,
    float* __restrict__ outp)
{
  constexpr int NT = C/16;
  const int tid = threadIdx.x;
  const int wid = tid >> 6, lane = tid & 63;
  const int lrow = lane & 15, lgrp = lane >> 4;
  const int m0 = (blockIdx.x*4 + wid)*16;

  bf16x8 Ahi[4], Alo[4];
  {
    int row = m0 + lrow; if (row >= NN) row = NN-1;
    const float* Xr = X + (size_t)row*128 + lgrp*8;
    #pragma unroll
    for (int ks=0; ks<4; ks++){
      float4 u0 = *(const float4*)(Xr + ks*32);
      float4 u1 = *(const float4*)(Xr + ks*32 + 4);
      float v[8] = {u0.x,u0.y,u0.z,u0.w,u1.x,u1.y,u1.z,u1.w};
      bf16x8 h8, l8;
      #pragma unroll
      for (int j=0;j<8;j++){
        __bf16 hb = (__bf16)v[j];
        h8[j] = hb;
        l8[j] = (__bf16)(v[j] - (float)hb);
      }
      Ahi[ks] = h8; Alo[ks] = l8;
    }
  }

  f32x4 acc[NT];
  #pragma unroll
  for (int t=0;t<NT;t++){ acc[t] = (f32x4){0.f,0.f,0.f,0.f}; }

  const bf16x8* B8h = (const bf16x8*)Bhi;
  const bf16x8* B8l = (const bf16x8*)Blo;
  #pragma unroll
  for (int ks=0;ks<4;ks++){
    bf16x8 bh[NT];
    #pragma unroll
    for (int t=0;t<NT;t++) bh[t] = B8h[(t*4+ks)*64 + lane];
    #pragma unroll
    for (int t=0;t<NT;t++)
      acc[t] = __builtin_amdgcn_mfma_f32_16x16x32_bf16(Ahi[ks], bh[t], acc[t], 0,0,0);
    #pragma unroll
    for (int t=0;t<NT;t++)
      acc[t] = __builtin_amdgcn_mfma_f32_16x16x32_bf16(Alo[ks], bh[t], acc[t], 0,0,0);
    #pragma unroll
    for (int t=0;t<NT;t++){
      bf16x8 bl = B8l[(t*4+ks)*64 + lane];
      acc[t] = __builtin_amdgcn_mfma_f32_16x16x32_bf16(Ahi[ks], bl, acc[t], 0,0,0);
    }
  }

  #pragma unroll
  for (int t=0;t<NT;t++){
    float bv = bias[t*16 + lrow];
    #pragma unroll
    for (int i=0;i<4;i++) acc[t][i] += bv;
  }

  if constexpr (DO_LN){
    float s[4] = {0,0,0,0}, q[4] = {0,0,0,0};
    #pragma unroll
    for (int t=0;t<NT;t++){
      #pragma unroll
      for (int i=0;i<4;i++){ s[i] += acc[t][i]; q[i] += acc[t][i]*acc[t][i]; }
    }
    #pragma unroll
    for (int off=1; off<16; off<<=1){
      #pragma unroll
      for (int i=0;i<4;i++){ s[i] += __shfl_xor(s[i], off); q[i] += __shfl_xor(q[i], off); }
    }
    float mean[4], rr[4];
    #pragma unroll
    for (int i=0;i<4;i++){
      mean[i] = s[i]*(1.0f/C);
      float var = q[i]*(1.0f/C) - mean[i]*mean[i];
      rr[i] = rsqrtf(var + 1e-5f);
    }
    #pragma unroll
    for (int t=0;t<NT;t++){
      float lw = lnw[t*16 + lrow], lb = lnb[t*16 + lrow];
      #pragma unroll
      for (int i=0;i<4;i++){
        float v = (acc[t][i]-mean[i])*rr[i]*lw + lb;
        if constexpr (DO_RELU) v = fmaxf(v, 0.f);
        acc[t][i] = v;
      }
    }
  } else if constexpr (DO_RELU){
    #pragma unroll
    for (int t=0;t<NT;t++){
      #pragma unroll
      for (int i=0;i<4;i++) acc[t][i] = fmaxf(acc[t][i], 0.f);
    }
  }
  if constexpr (OUTP){
    float4 w3r[NT];
    #pragma unroll
    for (int t=0;t<NT;t++) w3r[t] = ((const float4*)w3)[t*16 + lrow];
    float4 b3v = *(const float4*)b3;
    #pragma unroll
    for (int i=0;i<4;i++){
      float4 po = make_float4(0.f,0.f,0.f,0.f);
      #pragma unroll
      for (int t=0;t<NT;t++){
        po.x = fmaf(acc[t][i], w3r[t].x, po.x);
        po.y = fmaf(acc[t][i], w3r[t].y, po.y);
        po.z = fmaf(acc[t][i], w3r[t].z, po.z);
        po.w = fmaf(acc[t][i], w3r[t].w, po.w);
      }
      #pragma unroll
      for (int off=1; off<16; off<<=1){
        po.x += __shfl_xor(po.x, off);
        po.y += __shfl_xor(po.y, off);
        po.z += __shfl_xor(po.z, off);
        po.w += __shfl_xor(po.w, off);
      }
      if (lrow == 0){
        int n = m0 + lgrp*4 + i;
        if (n < NN){
          float4 o;
          o.x = po.x + b3v.x; o.y = po.y + b3v.y;
          o.z = po.z + b3v.z; o.w = po.w + b3v.w;
          ((float4*)outp)[n] = o;
        }
      }
    }
  } else {
    #pragma unroll
    for (int t=0;t<NT;t++){
      #pragma unroll
      for (int i=0;i<4;i++){
        int n = m0 + lgrp*4 + i;
        if (n < NN) Y[(size_t)n*C + t*16 + lrow] = acc[t][i];
      }
    }
  }
}

// ---------------- per-node softmax + aggregate + LN + residual ----------------
// Two nodes per wave: each 32-lane group owns ONE node (4 channels/lane via
// one uint2 bf16 load, head hh = sl>>2). Private per-lane exp, unrolled
// independent loads, zero cross-lane ops in the edge loop.
__global__ __launch_bounds__(256) void gat_aggregate(
    const __bf16* __restrict__ xw, const float* __restrict__ als, const float* __restrict__ ald,
    const int* __restrict__ offs, const int* __restrict__ csrsrc,
    const float* __restrict__ bg, const float* __restrict__ lnw, const float* __restrict__ lnb,
    float* __restrict__ h)
{
  const int tid = threadIdx.x;
  const int grp = tid >> 5, sl = tid & 31;
  const int n = blockIdx.x*8 + grp;
  const int hh = sl >> 2;                   // head of channels 4sl..4sl+3
  const float ad = ald[n*8 + hh];
  const uint2* xw64 = (const uint2*)xw;     // 4 bf16 per uint2; node row = 32 uint2

  // self-loop
  float t = als[n*8 + hh] + ad; t = t > 0.f ? t : 0.2f*t;
  float pp = __expf(t);
  float s = pp;
  float4 xv = bf4f(xw64[(unsigned)n*32u + sl]);
  float4 acc;
  acc.x = pp*xv.x; acc.y = pp*xv.y; acc.z = pp*xv.z; acc.w = pp*xv.w;

  const int start = offs[n], end = offs[n+1];
  int e = start;
  for (; e+4 <= end; e += 4){
    int s4[4]; float a[4]; uint2 x2[4];
    #pragma unroll
    for (int j=0;j<4;j++) s4[j] = csrsrc[e+j];
    #pragma unroll
    for (int j=0;j<4;j++){
      a[j]  = als[s4[j]*8 + hh];
      x2[j] = xw64[(unsigned)s4[j]*32u + sl];
    }
    #pragma unroll
    for (int j=0;j<4;j++){
      float u = a[j] + ad; u = u > 0.f ? u : 0.2f*u;
      float q = __expf(u);
      s += q;
      float4 m = bf4f(x2[j]);
      acc.x = fmaf(q, m.x, acc.x);
      acc.y = fmaf(q, m.y, acc.y);
      acc.z = fmaf(q, m.z, acc.z);
      acc.w = fmaf(q, m.w, acc.w);
    }
  }
  if (e+2 <= end){
    int sA = csrsrc[e], sB = csrsrc[e+1];
    float aA = als[sA*8+hh], aB = als[sB*8+hh];
    uint2 xA = xw64[(unsigned)sA*32u + sl];
    uint2 xB = xw64[(unsigned)sB*32u + sl];
    float u;
    u = aA+ad; u = u>0.f?u:0.2f*u; float qA = __expf(u);
    u = aB+ad; u = u>0.f?u:0.2f*u; float qB = __expf(u);
    s += qA+qB;
    float4 mA = bf4f(xA), mB = bf4f(xB);
    acc.x = fmaf(qA, mA.x, fmaf(qB, mB.x, acc.x));
    acc.y = fmaf(qA, mA.y, fmaf(qB, mB.y, acc.y));
    acc.z = fmaf(qA, mA.z, fmaf(qB, mB.z, acc.z));
    acc.w = fmaf(qA, mA.w, fmaf(qB, mB.w, acc.w));
    e += 2;
  }
  if (e < end){
    int sA = csrsrc[e];
    float aA = als[sA*8+hh];
    uint2 xA = xw64[(unsigned)sA*32u + sl];
    float u = aA+ad; u = u>0.f?u:0.2f*u; float qA = __expf(u);
    s += qA;
    float4 mA = bf4f(xA);
    acc.x = fmaf(qA, mA.x, acc.x);
    acc.y = fmaf(qA, mA.y, acc.y);
    acc.z = fmaf(qA, mA.z, acc.z);
    acc.w = fmaf(qA, mA.w, acc.w);
  }

  float4 bgv = ((const float4*)bg)[sl];
  float inv = 1.0f/s;
  float4 val;
  val.x = acc.x*inv + bgv.x;
  val.y = acc.y*inv + bgv.y;
  val.z = acc.z*inv + bgv.z;
  val.w = acc.w*inv + bgv.w;
  // LayerNorm across 128 channels: butterfly over the 32 lanes of this group
  float sum = val.x+val.y+val.z+val.w;
  float sq  = dot4(val,val);
  #pragma unroll
  for (int off=16; off>=1; off>>=1){ sum += __shfl_xor(sum,off); sq += __shfl_xor(sq,off); }
  float mean = sum*(1.f/128.f);
  float var  = sq*(1.f/128.f) - mean*mean;
  float rr = rsqrtf(var + 1e-5f);
  float4 lw = ((const float4*)lnw)[sl];
  float4 lb = ((const float4*)lnb)[sl];
  float4* hp = (float4*)(h + (size_t)n*128) + sl;
  float4 hv = *hp;
  hv.x += fmaxf((val.x-mean)*rr*lw.x + lb.x, 0.f);
  hv.y += fmaxf((val.y-mean)*rr*lw.y + lb.y, 0.f);
  hv.z += fmaxf((val.z-mean)*rr*lw.z + lb.z, 0.f);
  hv.w += fmaxf((val.w-mean)*rr*lw.w + lb.w, 0.f);
  *hp = hv;
}

extern "C" void kernel_launch(void* const* d_in, const int* in_sizes, int n_in,
                              void* d_out, int out_size, void* d_ws, size_t ws_size,
                              hipStream_t stream)
{
  const float* x       = (const float*)d_in[0];
  const int*   ei      = (const int*)d_in[1];
  const float* w_in    = (const float*)d_in[2];
  const float* b_in    = (const float*)d_in[3];
  const float* ln_in_w = (const float*)d_in[4];
  const float* ln_in_b = (const float*)d_in[5];
  const float* Wg      = (const float*)d_in[6];
  const float* a_src   = (const float*)d_in[7];
  const float* a_dst   = (const float*)d_in[8];
  const float* bg      = (const float*)d_in[9];
  const float* lnw     = (const float*)d_in[10];
  const float* lnb     = (const float*)d_in[11];
  const float* w1      = (const float*)d_in[12];
  const float* b1      = (const float*)d_in[13];
  const float* lnow    = (const float*)d_in[14];
  const float* lnob    = (const float*)d_in[15];
  const float* w2      = (const float*)d_in[16];
  const float* b2      = (const float*)d_in[17];
  const float* w3      = (const float*)d_in[18];
  const float* b3      = (const float*)d_in[19];
  float* out = (float*)d_out;

  char* p = (char*)d_ws;
  auto carve = [&](size_t bytes)->void*{
    void* r = (void*)p; p += (bytes + 255) & ~(size_t)255; return r;
  };
  float* h    = (float*)carve((size_t)NN*128*4);
  float* xw   = (float*)carve((size_t)NN*128*4);   // fp32 o1 output
  __bf16* xwb = (__bf16*)carve((size_t)NN*128*2);  // bf16 GAT messages
  float* als  = (float*)carve((size_t)NN*8*4);
  float* ald  = (float*)carve((size_t)NN*8*4);
  int* offs   = (int*)carve((size_t)(NN+1)*4);
  int* cursor = (int*)carve((size_t)NN*4);
  int* cnt    = (int*)carve((size_t)NN*4);
  int* csrsrc = (int*)carve((size_t)NE*4);
  int* bsum   = (int*)carve(64*4);
  __bf16* pWhi  = (__bf16*)carve((size_t)24576*2);   // 16x16 frags: w1 @0, w2 @16384
  __bf16* pWlo  = (__bf16*)carve((size_t)24576*2);
  __bf16* pW32h = (__bf16*)carve((size_t)65536*2);   // 32x32 frags: Wg layers 0..3
  __bf16* pW32l = (__bf16*)carve((size_t)65536*2);

  const int* esrc = ei;
  const int* edst = ei + NE;

  // one-time weight repack into MFMA fragment layouts (bf16 hi/lo)
  repack_w<<<12, 256, 0, stream>>>(w1, w2, pWhi, pWlo);
  repack_w32<<<32, 256, 0, stream>>>(Wg, pW32h, pW32l);

  hipMemsetAsync(cnt, 0, (size_t)NN*4, stream);
  count_edges<<<(NE+255)/256, 256, 0, stream>>>(edst, cnt);
  scan1<<<49, 256, 0, stream>>>(cnt, offs, bsum);
  scan2<<<1, 64, 0, stream>>>(bsum);
  scan3<<<(NN+255)/256, 256, 0, stream>>>(offs, bsum, cursor);
  fill_csr<<<(NE+255)/256, 256, 0, stream>>>(esrc, edst, cursor, csrsrc);

  input_mlp<<<NN/8, 256, 0, stream>>>(x, w_in, b_in, ln_in_w, ln_in_b, h);

  const int GRID32 = (NN + 127) / 128;  // 782 (32x32 GAT gemm: 128 rows/block)
  const int GRID   = (NN + 63) / 64;    // 1563 (16x16 full-width)
  for (int i=0;i<4;i++){
    gemm32_gat<<<GRID32, 256, 0, stream>>>(
        h, pW32h + (size_t)i*16384, pW32l + (size_t)i*16384,
        a_src + i*128, a_dst + i*128, xwb, als, ald);
    gat_aggregate<<<NN/8, 256, 0, stream>>>(xwb, als, ald, offs, csrsrc,
        bg + i*128, lnw + i*128, lnb + i*128, h);
  }

  gemm_mfma<128,true,true,false><<<GRID, 256, 0, stream>>>(
      h, pWhi, pWlo, b1, lnow, lnob, xw, nullptr, nullptr, nullptr);
  gemm_mfma<64,false,true,true><<<GRID, 256, 0, stream>>>(
      xw, pWhi + 16384, pWlo + 16384, b2, nullptr, nullptr, nullptr, w3, b3, out);
}

// Round 23
// 486.320 us; speedup vs baseline: 1.0533x; 1.0533x over previous
//
#include <hip/hip_runtime.h>
#include <hip/hip_bf16.h>

#define NN 100000
#define NE 600000

typedef __bf16 bf16x8 __attribute__((ext_vector_type(8)));
typedef float  f32x4  __attribute__((ext_vector_type(4)));

__device__ __forceinline__ float dot4(float4 a, float4 b){
  return a.x*b.x + a.y*b.y + a.z*b.z + a.w*b.w;
}
// unpack 2 packed bf16 (low = even channel) to floats
__device__ __forceinline__ void bf2f(unsigned v, float& a, float& b){
  union { unsigned u; float f; } ua, ub;
  ua.u = v << 16;
  ub.u = v & 0xFFFF0000u;
  a = ua.f; b = ub.f;
}
__device__ __forceinline__ void bf8f(uint4 v, float* r){
  bf2f(v.x, r[0], r[1]);
  bf2f(v.y, r[2], r[3]);
  bf2f(v.z, r[4], r[5]);
  bf2f(v.w, r[6], r[7]);
}

// ---------------- CSR build (dst-grouped) ----------------
__global__ void count_edges(const int* __restrict__ dst, int* __restrict__ cnt){
  int e = blockIdx.x*256 + threadIdx.x;
  if (e < NE){
    unsigned d = (unsigned)dst[e];
    if (d < NN) atomicAdd(&cnt[d], 1);
  }
}

__global__ void scan1(const int* __restrict__ cnt, int* __restrict__ offs, int* __restrict__ bsum){
  __shared__ int sh[256];
  const int tid = threadIdx.x;
  const int base = blockIdx.x*2048 + tid*8;
  int pre[8]; int s = 0;
  #pragma unroll
  for (int j=0;j<8;j++){
    int idx = base + j;
    int v = (idx < NN) ? cnt[idx] : 0;
    pre[j] = s; s += v;
  }
  sh[tid] = s;
  __syncthreads();
  for (int d=1; d<256; d<<=1){
    int t = (tid >= d) ? sh[tid-d] : 0;
    __syncthreads();
    sh[tid] += t;
    __syncthreads();
  }
  int off = (tid > 0) ? sh[tid-1] : 0;
  #pragma unroll
  for (int j=0;j<8;j++){
    int idx = base + j;
    if (idx < NN) offs[idx] = off + pre[j];
  }
  if (tid == 255) bsum[blockIdx.x] = sh[255];
}

__global__ void scan2(int* __restrict__ bsum){
  if (threadIdx.x == 0){
    int s = 0;
    for (int i=0;i<49;i++){ int t = bsum[i]; bsum[i] = s; s += t; }
  }
}

__global__ void scan3(int* __restrict__ offs, const int* __restrict__ bsum, int* __restrict__ cursor){
  int i = blockIdx.x*256 + threadIdx.x;
  if (i < NN){
    int v = offs[i] + bsum[i>>11];
    offs[i] = v; cursor[i] = v;
  }
  if (i == 0) offs[NN] = NE;
}

__global__ void fill_csr(const int* __restrict__ src, const int* __restrict__ dst,
                         int* __restrict__ cursor, int* __restrict__ csrsrc){
  int e = blockIdx.x*256 + threadIdx.x;
  if (e < NE){
    unsigned d = (unsigned)dst[e];
    unsigned s = (unsigned)src[e];
    if (d < NN && s < NN){
      int p = atomicAdd(&cursor[d], 1);
      csrsrc[p] = (int)s;
    }
  }
}

// ---------------- weight repack: fp32 W[K][C] -> bf16 hi/lo MFMA fragments ----
__global__ void repack_w(const float* __restrict__ Wg, const float* __restrict__ w1,
                         const float* __restrict__ w2,
                         __bf16* __restrict__ phi, __bf16* __restrict__ plo)
{
  int gid = blockIdx.x*256 + threadIdx.x;
  const float* W; int C; size_t obase; int rem;
  if (gid < 8192)      { W = Wg + (size_t)(gid/2048)*16384; C = 128; obase = (size_t)(gid/2048)*16384; rem = gid % 2048; }
  else if (gid < 10240){ W = w1; C = 128; obase = 65536; rem = gid - 8192; }
  else if (gid < 11264){ W = w2; C = 64;  obase = 81920; rem = gid - 10240; }
  else return;
  const int lane = rem & 63;
  const int tks  = rem >> 6;
  const int ks = tks & 3, t = tks >> 2;
  const int col = t*16 + (lane & 15);
  const int kb  = ks*32 + (lane >> 4)*8;
  const size_t o = obase + (size_t)rem*8;
  #pragma unroll
  for (int j=0;j<8;j++){
    float v = W[(size_t)(kb+j)*C + col];
    __bf16 hb = (__bf16)v;
    phi[o+j] = hb;
    plo[o+j] = (__bf16)(v - (float)hb);
  }
}

// ---------------- input MLP: h = relu(LN(x@w_in+b_in)) ----------------
__global__ __launch_bounds__(256) void input_mlp(const float* __restrict__ x,
    const float* __restrict__ win, const float* __restrict__ b,
    const float* __restrict__ lnw, const float* __restrict__ lnb,
    float* __restrict__ h)
{
  const int tid = threadIdx.x;
  const int g = tid >> 5, l = tid & 31;
  const int n = blockIdx.x*8 + g;
  const float4* W4 = (const float4*)win;
  float xr[6];
  #pragma unroll
  for (int k=0;k<6;k++) xr[k] = x[n*6+k];
  float4 s = ((const float4*)b)[l];
  #pragma unroll
  for (int k=0;k<6;k++){
    float4 w = W4[k*32 + l];
    s.x = fmaf(xr[k], w.x, s.x);
    s.y = fmaf(xr[k], w.y, s.y);
    s.z = fmaf(xr[k], w.z, s.z);
    s.w = fmaf(xr[k], w.w, s.w);
  }
  float sum = s.x+s.y+s.z+s.w;
  float sq  = dot4(s,s);
  #pragma unroll
  for (int o=16;o>=1;o>>=1){ sum += __shfl_xor(sum,o); sq += __shfl_xor(sq,o); }
  float mean = sum*(1.f/128.f);
  float var  = sq*(1.f/128.f) - mean*mean;
  float rr = rsqrtf(var + 1e-5f);
  float4 lw = ((const float4*)lnw)[l];
  float4 lb = ((const float4*)lnb)[l];
  float4 y;
  y.x = fmaxf((s.x-mean)*rr*lw.x + lb.x, 0.f);
  y.y = fmaxf((s.y-mean)*rr*lw.y + lb.y, 0.f);
  y.z = fmaxf((s.z-mean)*rr*lw.z + lb.z, 0.f);
  y.w = fmaxf((s.w-mean)*rr*lw.w + lb.w, 0.f);
  ((float4*)(h + (size_t)n*128))[l] = y;
}

// ---------------- MFMA split-bf16 GEMM: Y = act(LN?(X@W + b)), K=128 ----------
// SPLIT (GAT only): each wave handles 16 rows x 64 cols (NT=4).
template<int C, bool HAS_BIAS, bool DO_LN, bool DO_RELU, bool GAT, bool OUTP, bool SPLIT>
__global__ __launch_bounds__(256) void gemm_mfma(const float* __restrict__ X,
    const __bf16* __restrict__ Bhi, const __bf16* __restrict__ Blo,
    const float* __restrict__ bias,
    const float* __restrict__ lnw, const float* __restrict__ lnb,
    const float* __restrict__ asrc, const float* __restrict__ adst,
    float* __restrict__ Y, __bf16* __restrict__ Yb,
    float* __restrict__ als, float* __restrict__ ald,
    const float* __restrict__ w3, const float* __restrict__ b3,
    float* __restrict__ outp)
{
  constexpr int NT = SPLIT ? C/32 : C/16;
  const int tid = threadIdx.x;
  const int wid = tid >> 6, lane = tid & 63;
  const int lrow = lane & 15, lgrp = lane >> 4;
  const int m0    = SPLIT ? (blockIdx.x*32 + (wid>>1)*16) : ((blockIdx.x*4 + wid)*16);
  const int colt0 = SPLIT ? (wid & 1)*NT : 0;   // starting 16-col tile index

  bf16x8 Ahi[4], Alo[4];
  {
    int row = m0 + lrow; if (row >= NN) row = NN-1;
    const float* Xr = X + (size_t)row*128 + lgrp*8;
    #pragma unroll
    for (int ks=0; ks<4; ks++){
      float4 u0 = *(const float4*)(Xr + ks*32);
      float4 u1 = *(const float4*)(Xr + ks*32 + 4);
      float v[8] = {u0.x,u0.y,u0.z,u0.w,u1.x,u1.y,u1.z,u1.w};
      bf16x8 h8, l8;
      #pragma unroll
      for (int j=0;j<8;j++){
        __bf16 hb = (__bf16)v[j];
        h8[j] = hb;
        l8[j] = (__bf16)(v[j] - (float)hb);
      }
      Ahi[ks] = h8; Alo[ks] = l8;
    }
  }

  f32x4 acc[NT];
  #pragma unroll
  for (int t=0;t<NT;t++){ acc[t] = (f32x4){0.f,0.f,0.f,0.f}; }

  const bf16x8* B8h = (const bf16x8*)Bhi;
  const bf16x8* B8l = (const bf16x8*)Blo;
  #pragma unroll
  for (int ks=0;ks<4;ks++){
    bf16x8 bh[NT];
    #pragma unroll
    for (int t=0;t<NT;t++) bh[t] = B8h[((colt0+t)*4+ks)*64 + lane];
    #pragma unroll
    for (int t=0;t<NT;t++)
      acc[t] = __builtin_amdgcn_mfma_f32_16x16x32_bf16(Ahi[ks], bh[t], acc[t], 0,0,0);
    #pragma unroll
    for (int t=0;t<NT;t++)
      acc[t] = __builtin_amdgcn_mfma_f32_16x16x32_bf16(Alo[ks], bh[t], acc[t], 0,0,0);
    #pragma unroll
    for (int t=0;t<NT;t++){
      bf16x8 bl = B8l[((colt0+t)*4+ks)*64 + lane];
      acc[t] = __builtin_amdgcn_mfma_f32_16x16x32_bf16(Ahi[ks], bl, acc[t], 0,0,0);
    }
  }

  if constexpr (HAS_BIAS){
    #pragma unroll
    for (int t=0;t<NT;t++){
      float bv = bias[(colt0+t)*16 + lrow];
      #pragma unroll
      for (int i=0;i<4;i++) acc[t][i] += bv;
    }
  }

  if constexpr (GAT){
    #pragma unroll
    for (int t=0;t<NT;t++){
      float av = asrc[(colt0+t)*16 + lrow];
      float dv2 = adst[(colt0+t)*16 + lrow];
      float ps[4], pd[4];
      #pragma unroll
      for (int i=0;i<4;i++){
        int n = m0 + lgrp*4 + i;
        if (n < NN) Yb[(size_t)n*C + (colt0+t)*16 + lrow] = (__bf16)acc[t][i];
        ps[i] = acc[t][i]*av; pd[i] = acc[t][i]*dv2;
      }
      #pragma unroll
      for (int off=1; off<16; off<<=1){
        #pragma unroll
        for (int i=0;i<4;i++){
          ps[i] += __shfl_xor(ps[i], off);
          pd[i] += __shfl_xor(pd[i], off);
        }
      }
      if (lrow == 0){
        #pragma unroll
        for (int i=0;i<4;i++){
          int n = m0 + lgrp*4 + i;
          if (n < NN){ als[n*8 + colt0 + t] = ps[i]; ald[n*8 + colt0 + t] = pd[i]; }
        }
      }
    }
  } else {
    if constexpr (DO_LN){
      float s[4] = {0,0,0,0}, q[4] = {0,0,0,0};
      #pragma unroll
      for (int t=0;t<NT;t++){
        #pragma unroll
        for (int i=0;i<4;i++){ s[i] += acc[t][i]; q[i] += acc[t][i]*acc[t][i]; }
      }
      #pragma unroll
      for (int off=1; off<16; off<<=1){
        #pragma unroll
        for (int i=0;i<4;i++){ s[i] += __shfl_xor(s[i], off); q[i] += __shfl_xor(q[i], off); }
      }
      float mean[4], rr[4];
      #pragma unroll
      for (int i=0;i<4;i++){
        mean[i] = s[i]*(1.0f/C);
        float var = q[i]*(1.0f/C) - mean[i]*mean[i];
        rr[i] = rsqrtf(var + 1e-5f);
      }
      #pragma unroll
      for (int t=0;t<NT;t++){
        float lw = lnw[t*16 + lrow], lb = lnb[t*16 + lrow];
        #pragma unroll
        for (int i=0;i<4;i++){
          float v = (acc[t][i]-mean[i])*rr[i]*lw + lb;
          if constexpr (DO_RELU) v = fmaxf(v, 0.f);
          acc[t][i] = v;
        }
      }
    } else if constexpr (DO_RELU){
      #pragma unroll
      for (int t=0;t<NT;t++){
        #pragma unroll
        for (int i=0;i<4;i++) acc[t][i] = fmaxf(acc[t][i], 0.f);
      }
    }
    if constexpr (OUTP){
      float4 w3r[NT];
      #pragma unroll
      for (int t=0;t<NT;t++) w3r[t] = ((const float4*)w3)[t*16 + lrow];
      float4 b3v = *(const float4*)b3;
      #pragma unroll
      for (int i=0;i<4;i++){
        float4 po = make_float4(0.f,0.f,0.f,0.f);
        #pragma unroll
        for (int t=0;t<NT;t++){
          po.x = fmaf(acc[t][i], w3r[t].x, po.x);
          po.y = fmaf(acc[t][i], w3r[t].y, po.y);
          po.z = fmaf(acc[t][i], w3r[t].z, po.z);
          po.w = fmaf(acc[t][i], w3r[t].w, po.w);
        }
        #pragma unroll
        for (int off=1; off<16; off<<=1){
          po.x += __shfl_xor(po.x, off);
          po.y += __shfl_xor(po.y, off);
          po.z += __shfl_xor(po.z, off);
          po.w += __shfl_xor(po.w, off);
        }
        if (lrow == 0){
          int n = m0 + lgrp*4 + i;
          if (n < NN){
            float4 o;
            o.x = po.x + b3v.x; o.y = po.y + b3v.y;
            o.z = po.z + b3v.z; o.w = po.w + b3v.w;
            ((float4*)outp)[n] = o;
          }
        }
      }
    } else {
      #pragma unroll
      for (int t=0;t<NT;t++){
        #pragma unroll
        for (int i=0;i<4;i++){
          int n = m0 + lgrp*4 + i;
          if (n < NN) Y[(size_t)n*C + t*16 + lrow] = acc[t][i];
        }
      }
    }
  }
}

// ---------------- per-node softmax + aggregate + LN + residual ----------------
// FOUR nodes per wave: each 16-lane group owns ONE node (8 channels/lane via
// one uint4 bf16 load, head hh = sl>>1). Every wave instruction serves four
// edges (one per group) -> per-edge amortized cost of csrsrc/als/exp/address
// halves again vs the 2-node layout. LN butterfly offsets <=8 stay inside the
// 16-lane group. Private per-lane exp, unrolled independent loads, zero
// cross-lane ops in the edge loop (r13/r16 principles kept).
__global__ __launch_bounds__(256) void gat_aggregate(
    const __bf16* __restrict__ xw, const float* __restrict__ als, const float* __restrict__ ald,
    const int* __restrict__ offs, const int* __restrict__ csrsrc,
    const float* __restrict__ bg, const float* __restrict__ lnw, const float* __restrict__ lnb,
    float* __restrict__ h)
{
  const int tid = threadIdx.x;
  const int grp = tid >> 4, sl = tid & 15;
  const int n = blockIdx.x*16 + grp;
  const int hh = sl >> 1;                   // head of channels 8sl..8sl+7
  const float ad = ald[n*8 + hh];
  const uint4* xw128 = (const uint4*)xw;    // 8 bf16 per uint4; node row = 16 uint4

  // self-loop
  float t = als[n*8 + hh] + ad; t = t > 0.f ? t : 0.2f*t;
  float pp = __expf(t);
  float s = pp;
  float m[8];
  bf8f(xw128[(unsigned)n*16u + sl], m);
  float acc[8];
  #pragma unroll
  for (int c=0;c<8;c++) acc[c] = pp*m[c];

  const int start = offs[n], end = offs[n+1];
  int e = start;
  for (; e+4 <= end; e += 4){
    int s4[4]; float a[4]; uint4 x4[4];
    #pragma unroll
    for (int j=0;j<4;j++) s4[j] = csrsrc[e+j];
    #pragma unroll
    for (int j=0;j<4;j++){
      a[j]  = als[s4[j]*8 + hh];
      x4[j] = xw128[(unsigned)s4[j]*16u + sl];
    }
    #pragma unroll
    for (int j=0;j<4;j++){
      float u = a[j] + ad; u = u > 0.f ? u : 0.2f*u;
      float q = __expf(u);
      s += q;
      float mm[8];
      bf8f(x4[j], mm);
      #pragma unroll
      for (int c=0;c<8;c++) acc[c] = fmaf(q, mm[c], acc[c]);
    }
  }
  if (e+2 <= end){
    int sA = csrsrc[e], sB = csrsrc[e+1];
    float aA = als[sA*8+hh], aB = als[sB*8+hh];
    uint4 xA = xw128[(unsigned)sA*16u + sl];
    uint4 xB = xw128[(unsigned)sB*16u + sl];
    float u;
    u = aA+ad; u = u>0.f?u:0.2f*u; float qA = __expf(u);
    u = aB+ad; u = u>0.f?u:0.2f*u; float qB = __expf(u);
    s += qA+qB;
    float mA[8], mB[8];
    bf8f(xA, mA); bf8f(xB, mB);
    #pragma unroll
    for (int c=0;c<8;c++) acc[c] = fmaf(qA, mA[c], fmaf(qB, mB[c], acc[c]));
    e += 2;
  }
  if (e < end){
    int sA = csrsrc[e];
    float aA = als[sA*8+hh];
    uint4 xA = xw128[(unsigned)sA*16u + sl];
    float u = aA+ad; u = u>0.f?u:0.2f*u; float qA = __expf(u);
    s += qA;
    float mA[8];
    bf8f(xA, mA);
    #pragma unroll
    for (int c=0;c<8;c++) acc[c] = fmaf(qA, mA[c], acc[c]);
  }

  float4 bg0 = ((const float4*)bg)[2*sl];
  float4 bg1 = ((const float4*)bg)[2*sl+1];
  float bgv[8] = {bg0.x,bg0.y,bg0.z,bg0.w,bg1.x,bg1.y,bg1.z,bg1.w};
  float inv = 1.0f/s;
  float val[8];
  #pragma unroll
  for (int c=0;c<8;c++) val[c] = acc[c]*inv + bgv[c];
  // LayerNorm across 128 channels: butterfly over the 16 lanes of this group
  float sum = 0.f, sq = 0.f;
  #pragma unroll
  for (int c=0;c<8;c++){ sum += val[c]; sq += val[c]*val[c]; }
  #pragma unroll
  for (int off=8; off>=1; off>>=1){ sum += __shfl_xor(sum,off); sq += __shfl_xor(sq,off); }
  float mean = sum*(1.f/128.f);
  float var  = sq*(1.f/128.f) - mean*mean;
  float rr = rsqrtf(var + 1e-5f);
  float4 lw0 = ((const float4*)lnw)[2*sl];
  float4 lw1 = ((const float4*)lnw)[2*sl+1];
  float4 lb0 = ((const float4*)lnb)[2*sl];
  float4 lb1 = ((const float4*)lnb)[2*sl+1];
  float lwv[8] = {lw0.x,lw0.y,lw0.z,lw0.w,lw1.x,lw1.y,lw1.z,lw1.w};
  float lbv[8] = {lb0.x,lb0.y,lb0.z,lb0.w,lb1.x,lb1.y,lb1.z,lb1.w};
  float4* hp = (float4*)(h + (size_t)n*128) + 2*sl;
  float4 h0 = hp[0], h1 = hp[1];
  float hv[8] = {h0.x,h0.y,h0.z,h0.w,h1.x,h1.y,h1.z,h1.w};
  #pragma unroll
  for (int c=0;c<8;c++) hv[c] += fmaxf((val[c]-mean)*rr*lwv[c] + lbv[c], 0.f);
  hp[0] = make_float4(hv[0],hv[1],hv[2],hv[3]);
  hp[1] = make_float4(hv[4],hv[5],hv[6],hv[7]);
}

extern "C" void kernel_launch(void* const* d_in, const int* in_sizes, int n_in,
                              void* d_out, int out_size, void* d_ws, size_t ws_size,
                              hipStream_t stream)
{
  const float* x       = (const float*)d_in[0];
  const int*   ei      = (const int*)d_in[1];
  const float* w_in    = (const float*)d_in[2];
  const float* b_in    = (const float*)d_in[3];
  const float* ln_in_w = (const float*)d_in[4];
  const float* ln_in_b = (const float*)d_in[5];
  const float* Wg      = (const float*)d_in[6];
  const float* a_src   = (const float*)d_in[7];
  const float* a_dst   = (const float*)d_in[8];
  const float* bg      = (const float*)d_in[9];
  const float* lnw     = (const float*)d_in[10];
  const float* lnb     = (const float*)d_in[11];
  const float* w1      = (const float*)d_in[12];
  const float* b1      = (const float*)d_in[13];
  const float* lnow    = (const float*)d_in[14];
  const float* lnob    = (const float*)d_in[15];
  const float* w2      = (const float*)d_in[16];
  const float* b2      = (const float*)d_in[17];
  const float* w3      = (const float*)d_in[18];
  const float* b3      = (const float*)d_in[19];
  float* out = (float*)d_out;

  char* p = (char*)d_ws;
  auto carve = [&](size_t bytes)->void*{
    void* r = (void*)p; p += (bytes + 255) & ~(size_t)255; return r;
  };
  float* h    = (float*)carve((size_t)NN*128*4);
  float* xw   = (float*)carve((size_t)NN*128*4);   // fp32 o1 output
  __bf16* xwb = (__bf16*)carve((size_t)NN*128*2);  // bf16 GAT messages
  float* als  = (float*)carve((size_t)NN*8*4);
  float* ald  = (float*)carve((size_t)NN*8*4);
  int* offs   = (int*)carve((size_t)(NN+1)*4);
  int* cursor = (int*)carve((size_t)NN*4);
  int* cnt    = (int*)carve((size_t)NN*4);
  int* csrsrc = (int*)carve((size_t)NE*4);
  int* bsum   = (int*)carve(64*4);
  __bf16* pWhi = (__bf16*)carve((size_t)90112*2);
  __bf16* pWlo = (__bf16*)carve((size_t)90112*2);

  const int* esrc = ei;
  const int* edst = ei + NE;

  // one-time weight repack into MFMA fragment layout (bf16 hi/lo)
  repack_w<<<44, 256, 0, stream>>>(Wg, w1, w2, pWhi, pWlo);

  hipMemsetAsync(cnt, 0, (size_t)NN*4, stream);
  count_edges<<<(NE+255)/256, 256, 0, stream>>>(edst, cnt);
  scan1<<<49, 256, 0, stream>>>(cnt, offs, bsum);
  scan2<<<1, 64, 0, stream>>>(bsum);
  scan3<<<(NN+255)/256, 256, 0, stream>>>(offs, bsum, cursor);
  fill_csr<<<(NE+255)/256, 256, 0, stream>>>(esrc, edst, cursor, csrsrc);

  input_mlp<<<NN/8, 256, 0, stream>>>(x, w_in, b_in, ln_in_w, ln_in_b, h);

  const int GRID  = (NN + 63) / 64;   // 1563 (full-width waves)
  const int GRIDS = (NN + 31) / 32;   // 3125 (col-split waves)
  for (int i=0;i<4;i++){
    gemm_mfma<128,false,false,false,true,false,true><<<GRIDS, 256, 0, stream>>>(
        h, pWhi + (size_t)i*16384, pWlo + (size_t)i*16384, nullptr, nullptr, nullptr,
        a_src + i*128, a_dst + i*128, nullptr, xwb, als, ald, nullptr, nullptr, nullptr);
    gat_aggregate<<<NN/16, 256, 0, stream>>>(xwb, als, ald, offs, csrsrc,
        bg + i*128, lnw + i*128, lnb + i*128, h);
  }

  gemm_mfma<128,true,true,true,false,false,false><<<GRID, 256, 0, stream>>>(
      h, pWhi + 65536, pWlo + 65536, b1, lnow, lnob, nullptr, nullptr, xw, nullptr,
      nullptr, nullptr, nullptr, nullptr, nullptr);
  gemm_mfma<64,true,false,true,false,true,false><<<GRID, 256, 0, stream>>>(
      xw, pWhi + 81920, pWlo + 81920, b2, nullptr, nullptr, nullptr, nullptr, nullptr, nullptr,
      nullptr, nullptr, w3, b3, out);
}

// Round 24
// 467.194 us; speedup vs baseline: 1.0964x; 1.0409x over previous
//
#include <hip/hip_runtime.h>
#include <hip/hip_bf16.h>

#define NN 100000
#define NE 600000

typedef __bf16 bf16x8 __attribute__((ext_vector_type(8)));
typedef float  f32x4  __attribute__((ext_vector_type(4)));

__device__ __forceinline__ float dot4(float4 a, float4 b){
  return a.x*b.x + a.y*b.y + a.z*b.z + a.w*b.w;
}
// unpack 2 packed bf16 (low = even channel) to floats
__device__ __forceinline__ void bf2f(unsigned v, float& a, float& b){
  union { unsigned u; float f; } ua, ub;
  ua.u = v << 16;
  ub.u = v & 0xFFFF0000u;
  a = ua.f; b = ub.f;
}
__device__ __forceinline__ void bf8f(uint4 v, float* r){
  bf2f(v.x, r[0], r[1]);
  bf2f(v.y, r[2], r[3]);
  bf2f(v.z, r[4], r[5]);
  bf2f(v.w, r[6], r[7]);
}

// ---------------- CSR build (dst-grouped) ----------------
__global__ void count_edges(const int* __restrict__ dst, int* __restrict__ cnt){
  int e = blockIdx.x*256 + threadIdx.x;
  if (e < NE){
    unsigned d = (unsigned)dst[e];
    if (d < NN) atomicAdd(&cnt[d], 1);
  }
}

__global__ void scan1(const int* __restrict__ cnt, int* __restrict__ offs, int* __restrict__ bsum){
  __shared__ int sh[256];
  const int tid = threadIdx.x;
  const int base = blockIdx.x*2048 + tid*8;
  int pre[8]; int s = 0;
  #pragma unroll
  for (int j=0;j<8;j++){
    int idx = base + j;
    int v = (idx < NN) ? cnt[idx] : 0;
    pre[j] = s; s += v;
  }
  sh[tid] = s;
  __syncthreads();
  for (int d=1; d<256; d<<=1){
    int t = (tid >= d) ? sh[tid-d] : 0;
    __syncthreads();
    sh[tid] += t;
    __syncthreads();
  }
  int off = (tid > 0) ? sh[tid-1] : 0;
  #pragma unroll
  for (int j=0;j<8;j++){
    int idx = base + j;
    if (idx < NN) offs[idx] = off + pre[j];
  }
  if (tid == 255) bsum[blockIdx.x] = sh[255];
}

__global__ void scan2(int* __restrict__ bsum){
  if (threadIdx.x == 0){
    int s = 0;
    for (int i=0;i<49;i++){ int t = bsum[i]; bsum[i] = s; s += t; }
  }
}

__global__ void scan3(int* __restrict__ offs, const int* __restrict__ bsum, int* __restrict__ cursor){
  int i = blockIdx.x*256 + threadIdx.x;
  if (i < NN){
    int v = offs[i] + bsum[i>>11];
    offs[i] = v; cursor[i] = v;
  }
  if (i == 0) offs[NN] = NE;
}

__global__ void fill_csr(const int* __restrict__ src, const int* __restrict__ dst,
                         int* __restrict__ cursor, int* __restrict__ csrsrc){
  int e = blockIdx.x*256 + threadIdx.x;
  if (e < NE){
    unsigned d = (unsigned)dst[e];
    unsigned s = (unsigned)src[e];
    if (d < NN && s < NN){
      int p = atomicAdd(&cursor[d], 1);
      csrsrc[p] = (int)s;
    }
  }
}

// ---------------- weight repack: fp32 W[K][C] -> bf16 hi/lo MFMA fragments ----
__global__ void repack_w(const float* __restrict__ Wg, const float* __restrict__ w1,
                         const float* __restrict__ w2,
                         __bf16* __restrict__ phi, __bf16* __restrict__ plo)
{
  int gid = blockIdx.x*256 + threadIdx.x;
  const float* W; int C; size_t obase; int rem;
  if (gid < 8192)      { W = Wg + (size_t)(gid/2048)*16384; C = 128; obase = (size_t)(gid/2048)*16384; rem = gid % 2048; }
  else if (gid < 10240){ W = w1; C = 128; obase = 65536; rem = gid - 8192; }
  else if (gid < 11264){ W = w2; C = 64;  obase = 81920; rem = gid - 10240; }
  else return;
  const int lane = rem & 63;
  const int tks  = rem >> 6;
  const int ks = tks & 3, t = tks >> 2;
  const int col = t*16 + (lane & 15);
  const int kb  = ks*32 + (lane >> 4)*8;
  const size_t o = obase + (size_t)rem*8;
  #pragma unroll
  for (int j=0;j<8;j++){
    float v = W[(size_t)(kb+j)*C + col];
    __bf16 hb = (__bf16)v;
    phi[o+j] = hb;
    plo[o+j] = (__bf16)(v - (float)hb);
  }
}

// ---------------- input MLP: h = relu(LN(x@w_in+b_in)) ----------------
__global__ __launch_bounds__(256) void input_mlp(const float* __restrict__ x,
    const float* __restrict__ win, const float* __restrict__ b,
    const float* __restrict__ lnw, const float* __restrict__ lnb,
    float* __restrict__ h)
{
  const int tid = threadIdx.x;
  const int g = tid >> 5, l = tid & 31;
  const int n = blockIdx.x*8 + g;
  const float4* W4 = (const float4*)win;
  float xr[6];
  #pragma unroll
  for (int k=0;k<6;k++) xr[k] = x[n*6+k];
  float4 s = ((const float4*)b)[l];
  #pragma unroll
  for (int k=0;k<6;k++){
    float4 w = W4[k*32 + l];
    s.x = fmaf(xr[k], w.x, s.x);
    s.y = fmaf(xr[k], w.y, s.y);
    s.z = fmaf(xr[k], w.z, s.z);
    s.w = fmaf(xr[k], w.w, s.w);
  }
  float sum = s.x+s.y+s.z+s.w;
  float sq  = dot4(s,s);
  #pragma unroll
  for (int o=16;o>=1;o>>=1){ sum += __shfl_xor(sum,o); sq += __shfl_xor(sq,o); }
  float mean = sum*(1.f/128.f);
  float var  = sq*(1.f/128.f) - mean*mean;
  float rr = rsqrtf(var + 1e-5f);
  float4 lw = ((const float4*)lnw)[l];
  float4 lb = ((const float4*)lnb)[l];
  float4 y;
  y.x = fmaxf((s.x-mean)*rr*lw.x + lb.x, 0.f);
  y.y = fmaxf((s.y-mean)*rr*lw.y + lb.y, 0.f);
  y.z = fmaxf((s.z-mean)*rr*lw.z + lb.z, 0.f);
  y.w = fmaxf((s.w-mean)*rr*lw.w + lb.w, 0.f);
  ((float4*)(h + (size_t)n*128))[l] = y;
}

// ---------------- MFMA split-bf16 GEMM: Y = act(LN?(X@W + b)), K=128 ----------
// SPLIT (GAT only): each wave handles 16 rows x 64 cols (NT=4).
// SKIPLO (GAT only): drop the Ahi*Blo term -> no Blo loads (halves the
// request-bound B traffic). Error ~X@Wlo ~ 3-7e-4, below the xw bf16
// quantization already applied. o1/o2 keep the full 3-MFMA path.
template<int C, bool HAS_BIAS, bool DO_LN, bool DO_RELU, bool GAT, bool OUTP, bool SPLIT, bool SKIPLO>
__global__ __launch_bounds__(256) void gemm_mfma(const float* __restrict__ X,
    const __bf16* __restrict__ Bhi, const __bf16* __restrict__ Blo,
    const float* __restrict__ bias,
    const float* __restrict__ lnw, const float* __restrict__ lnb,
    const float* __restrict__ asrc, const float* __restrict__ adst,
    float* __restrict__ Y, __bf16* __restrict__ Yb,
    float* __restrict__ als, float* __restrict__ ald,
    const float* __restrict__ w3, const float* __restrict__ b3,
    float* __restrict__ outp)
{
  constexpr int NT = SPLIT ? C/32 : C/16;
  const int tid = threadIdx.x;
  const int wid = tid >> 6, lane = tid & 63;
  const int lrow = lane & 15, lgrp = lane >> 4;
  const int m0    = SPLIT ? (blockIdx.x*32 + (wid>>1)*16) : ((blockIdx.x*4 + wid)*16);
  const int colt0 = SPLIT ? (wid & 1)*NT : 0;   // starting 16-col tile index

  bf16x8 Ahi[4], Alo[4];
  {
    int row = m0 + lrow; if (row >= NN) row = NN-1;
    const float* Xr = X + (size_t)row*128 + lgrp*8;
    #pragma unroll
    for (int ks=0; ks<4; ks++){
      float4 u0 = *(const float4*)(Xr + ks*32);
      float4 u1 = *(const float4*)(Xr + ks*32 + 4);
      float v[8] = {u0.x,u0.y,u0.z,u0.w,u1.x,u1.y,u1.z,u1.w};
      bf16x8 h8, l8;
      #pragma unroll
      for (int j=0;j<8;j++){
        __bf16 hb = (__bf16)v[j];
        h8[j] = hb;
        l8[j] = (__bf16)(v[j] - (float)hb);
      }
      Ahi[ks] = h8; Alo[ks] = l8;
    }
  }

  f32x4 acc[NT];
  #pragma unroll
  for (int t=0;t<NT;t++){ acc[t] = (f32x4){0.f,0.f,0.f,0.f}; }

  const bf16x8* B8h = (const bf16x8*)Bhi;
  const bf16x8* B8l = (const bf16x8*)Blo;
  #pragma unroll
  for (int ks=0;ks<4;ks++){
    bf16x8 bh[NT];
    #pragma unroll
    for (int t=0;t<NT;t++) bh[t] = B8h[((colt0+t)*4+ks)*64 + lane];
    #pragma unroll
    for (int t=0;t<NT;t++)
      acc[t] = __builtin_amdgcn_mfma_f32_16x16x32_bf16(Ahi[ks], bh[t], acc[t], 0,0,0);
    #pragma unroll
    for (int t=0;t<NT;t++)
      acc[t] = __builtin_amdgcn_mfma_f32_16x16x32_bf16(Alo[ks], bh[t], acc[t], 0,0,0);
    if constexpr (!SKIPLO){
      #pragma unroll
      for (int t=0;t<NT;t++){
        bf16x8 bl = B8l[((colt0+t)*4+ks)*64 + lane];
        acc[t] = __builtin_amdgcn_mfma_f32_16x16x32_bf16(Ahi[ks], bl, acc[t], 0,0,0);
      }
    }
  }

  if constexpr (HAS_BIAS){
    #pragma unroll
    for (int t=0;t<NT;t++){
      float bv = bias[(colt0+t)*16 + lrow];
      #pragma unroll
      for (int i=0;i<4;i++) acc[t][i] += bv;
    }
  }

  if constexpr (GAT){
    #pragma unroll
    for (int t=0;t<NT;t++){
      float av = asrc[(colt0+t)*16 + lrow];
      float dv2 = adst[(colt0+t)*16 + lrow];
      float ps[4], pd[4];
      #pragma unroll
      for (int i=0;i<4;i++){
        int n = m0 + lgrp*4 + i;
        if (n < NN) Yb[(size_t)n*C + (colt0+t)*16 + lrow] = (__bf16)acc[t][i];
        ps[i] = acc[t][i]*av; pd[i] = acc[t][i]*dv2;
      }
      #pragma unroll
      for (int off=1; off<16; off<<=1){
        #pragma unroll
        for (int i=0;i<4;i++){
          ps[i] += __shfl_xor(ps[i], off);
          pd[i] += __shfl_xor(pd[i], off);
        }
      }
      if (lrow == 0){
        #pragma unroll
        for (int i=0;i<4;i++){
          int n = m0 + lgrp*4 + i;
          if (n < NN){ als[n*8 + colt0 + t] = ps[i]; ald[n*8 + colt0 + t] = pd[i]; }
        }
      }
    }
  } else {
    if constexpr (DO_LN){
      float s[4] = {0,0,0,0}, q[4] = {0,0,0,0};
      #pragma unroll
      for (int t=0;t<NT;t++){
        #pragma unroll
        for (int i=0;i<4;i++){ s[i] += acc[t][i]; q[i] += acc[t][i]*acc[t][i]; }
      }
      #pragma unroll
      for (int off=1; off<16; off<<=1){
        #pragma unroll
        for (int i=0;i<4;i++){ s[i] += __shfl_xor(s[i], off); q[i] += __shfl_xor(q[i], off); }
      }
      float mean[4], rr[4];
      #pragma unroll
      for (int i=0;i<4;i++){
        mean[i] = s[i]*(1.0f/C);
        float var = q[i]*(1.0f/C) - mean[i]*mean[i];
        rr[i] = rsqrtf(var + 1e-5f);
      }
      #pragma unroll
      for (int t=0;t<NT;t++){
        float lw = lnw[t*16 + lrow], lb = lnb[t*16 + lrow];
        #pragma unroll
        for (int i=0;i<4;i++){
          float v = (acc[t][i]-mean[i])*rr[i]*lw + lb;
          if constexpr (DO_RELU) v = fmaxf(v, 0.f);
          acc[t][i] = v;
        }
      }
    } else if constexpr (DO_RELU){
      #pragma unroll
      for (int t=0;t<NT;t++){
        #pragma unroll
        for (int i=0;i<4;i++) acc[t][i] = fmaxf(acc[t][i], 0.f);
      }
    }
    if constexpr (OUTP){
      float4 w3r[NT];
      #pragma unroll
      for (int t=0;t<NT;t++) w3r[t] = ((const float4*)w3)[t*16 + lrow];
      float4 b3v = *(const float4*)b3;
      #pragma unroll
      for (int i=0;i<4;i++){
        float4 po = make_float4(0.f,0.f,0.f,0.f);
        #pragma unroll
        for (int t=0;t<NT;t++){
          po.x = fmaf(acc[t][i], w3r[t].x, po.x);
          po.y = fmaf(acc[t][i], w3r[t].y, po.y);
          po.z = fmaf(acc[t][i], w3r[t].z, po.z);
          po.w = fmaf(acc[t][i], w3r[t].w, po.w);
        }
        #pragma unroll
        for (int off=1; off<16; off<<=1){
          po.x += __shfl_xor(po.x, off);
          po.y += __shfl_xor(po.y, off);
          po.z += __shfl_xor(po.z, off);
          po.w += __shfl_xor(po.w, off);
        }
        if (lrow == 0){
          int n = m0 + lgrp*4 + i;
          if (n < NN){
            float4 o;
            o.x = po.x + b3v.x; o.y = po.y + b3v.y;
            o.z = po.z + b3v.z; o.w = po.w + b3v.w;
            ((float4*)outp)[n] = o;
          }
        }
      }
    } else {
      #pragma unroll
      for (int t=0;t<NT;t++){
        #pragma unroll
        for (int i=0;i<4;i++){
          int n = m0 + lgrp*4 + i;
          if (n < NN) Y[(size_t)n*C + t*16 + lrow] = acc[t][i];
        }
      }
    }
  }
}

// ---------------- per-node softmax + aggregate + LN + residual ----------------
// FOUR nodes per wave: each 16-lane group owns ONE node (8 channels/lane via
// one uint4 bf16 load, head hh = sl>>1). At the L3 random-gather wall
// (192 MB @ ~3.9 TB/s); VALU slack (31%) aids co-scheduling with GEMMs.
__global__ __launch_bounds__(256) void gat_aggregate(
    const __bf16* __restrict__ xw, const float* __restrict__ als, const float* __restrict__ ald,
    const int* __restrict__ offs, const int* __restrict__ csrsrc,
    const float* __restrict__ bg, const float* __restrict__ lnw, const float* __restrict__ lnb,
    float* __restrict__ h)
{
  const int tid = threadIdx.x;
  const int grp = tid >> 4, sl = tid & 15;
  const int n = blockIdx.x*16 + grp;
  const int hh = sl >> 1;                   // head of channels 8sl..8sl+7
  const float ad = ald[n*8 + hh];
  const uint4* xw128 = (const uint4*)xw;    // 8 bf16 per uint4; node row = 16 uint4

  // self-loop
  float t = als[n*8 + hh] + ad; t = t > 0.f ? t : 0.2f*t;
  float pp = __expf(t);
  float s = pp;
  float m[8];
  bf8f(xw128[(unsigned)n*16u + sl], m);
  float acc[8];
  #pragma unroll
  for (int c=0;c<8;c++) acc[c] = pp*m[c];

  const int start = offs[n], end = offs[n+1];
  int e = start;
  for (; e+4 <= end; e += 4){
    int s4[4]; float a[4]; uint4 x4[4];
    #pragma unroll
    for (int j=0;j<4;j++) s4[j] = csrsrc[e+j];
    #pragma unroll
    for (int j=0;j<4;j++){
      a[j]  = als[s4[j]*8 + hh];
      x4[j] = xw128[(unsigned)s4[j]*16u + sl];
    }
    #pragma unroll
    for (int j=0;j<4;j++){
      float u = a[j] + ad; u = u > 0.f ? u : 0.2f*u;
      float q = __expf(u);
      s += q;
      float mm[8];
      bf8f(x4[j], mm);
      #pragma unroll
      for (int c=0;c<8;c++) acc[c] = fmaf(q, mm[c], acc[c]);
    }
  }
  if (e+2 <= end){
    int sA = csrsrc[e], sB = csrsrc[e+1];
    float aA = als[sA*8+hh], aB = als[sB*8+hh];
    uint4 xA = xw128[(unsigned)sA*16u + sl];
    uint4 xB = xw128[(unsigned)sB*16u + sl];
    float u;
    u = aA+ad; u = u>0.f?u:0.2f*u; float qA = __expf(u);
    u = aB+ad; u = u>0.f?u:0.2f*u; float qB = __expf(u);
    s += qA+qB;
    float mA[8], mB[8];
    bf8f(xA, mA); bf8f(xB, mB);
    #pragma unroll
    for (int c=0;c<8;c++) acc[c] = fmaf(qA, mA[c], fmaf(qB, mB[c], acc[c]));
    e += 2;
  }
  if (e < end){
    int sA = csrsrc[e];
    float aA = als[sA*8+hh];
    uint4 xA = xw128[(unsigned)sA*16u + sl];
    float u = aA+ad; u = u>0.f?u:0.2f*u; float qA = __expf(u);
    s += qA;
    float mA[8];
    bf8f(xA, mA);
    #pragma unroll
    for (int c=0;c<8;c++) acc[c] = fmaf(qA, mA[c], acc[c]);
  }

  float4 bg0 = ((const float4*)bg)[2*sl];
  float4 bg1 = ((const float4*)bg)[2*sl+1];
  float bgv[8] = {bg0.x,bg0.y,bg0.z,bg0.w,bg1.x,bg1.y,bg1.z,bg1.w};
  float inv = 1.0f/s;
  float val[8];
  #pragma unroll
  for (int c=0;c<8;c++) val[c] = acc[c]*inv + bgv[c];
  // LayerNorm across 128 channels: butterfly over the 16 lanes of this group
  float sum = 0.f, sq = 0.f;
  #pragma unroll
  for (int c=0;c<8;c++){ sum += val[c]; sq += val[c]*val[c]; }
  #pragma unroll
  for (int off=8; off>=1; off>>=1){ sum += __shfl_xor(sum,off); sq += __shfl_xor(sq,off); }
  float mean = sum*(1.f/128.f);
  float var  = sq*(1.f/128.f) - mean*mean;
  float rr = rsqrtf(var + 1e-5f);
  float4 lw0 = ((const float4*)lnw)[2*sl];
  float4 lw1 = ((const float4*)lnw)[2*sl+1];
  float4 lb0 = ((const float4*)lnb)[2*sl];
  float4 lb1 = ((const float4*)lnb)[2*sl+1];
  float lwv[8] = {lw0.x,lw0.y,lw0.z,lw0.w,lw1.x,lw1.y,lw1.z,lw1.w};
  float lbv[8] = {lb0.x,lb0.y,lb0.z,lb0.w,lb1.x,lb1.y,lb1.z,lb1.w};
  float4* hp = (float4*)(h + (size_t)n*128) + 2*sl;
  float4 h0 = hp[0], h1 = hp[1];
  float hv[8] = {h0.x,h0.y,h0.z,h0.w,h1.x,h1.y,h1.z,h1.w};
  #pragma unroll
  for (int c=0;c<8;c++) hv[c] += fmaxf((val[c]-mean)*rr*lwv[c] + lbv[c], 0.f);
  hp[0] = make_float4(hv[0],hv[1],hv[2],hv[3]);
  hp[1] = make_float4(hv[4],hv[5],hv[6],hv[7]);
}

extern "C" void kernel_launch(void* const* d_in, const int* in_sizes, int n_in,
                              void* d_out, int out_size, void* d_ws, size_t ws_size,
                              hipStream_t stream)
{
  const float* x       = (const float*)d_in[0];
  const int*   ei      = (const int*)d_in[1];
  const float* w_in    = (const float*)d_in[2];
  const float* b_in    = (const float*)d_in[3];
  const float* ln_in_w = (const float*)d_in[4];
  const float* ln_in_b = (const float*)d_in[5];
  const float* Wg      = (const float*)d_in[6];
  const float* a_src   = (const float*)d_in[7];
  const float* a_dst   = (const float*)d_in[8];
  const float* bg      = (const float*)d_in[9];
  const float* lnw     = (const float*)d_in[10];
  const float* lnb     = (const float*)d_in[11];
  const float* w1      = (const float*)d_in[12];
  const float* b1      = (const float*)d_in[13];
  const float* lnow    = (const float*)d_in[14];
  const float* lnob    = (const float*)d_in[15];
  const float* w2      = (const float*)d_in[16];
  const float* b2      = (const float*)d_in[17];
  const float* w3      = (const float*)d_in[18];
  const float* b3      = (const float*)d_in[19];
  float* out = (float*)d_out;

  char* p = (char*)d_ws;
  auto carve = [&](size_t bytes)->void*{
    void* r = (void*)p; p += (bytes + 255) & ~(size_t)255; return r;
  };
  float* h    = (float*)carve((size_t)NN*128*4);
  float* xw   = (float*)carve((size_t)NN*128*4);   // fp32 o1 output
  __bf16* xwb = (__bf16*)carve((size_t)NN*128*2);  // bf16 GAT messages
  float* als  = (float*)carve((size_t)NN*8*4);
  float* ald  = (float*)carve((size_t)NN*8*4);
  int* offs   = (int*)carve((size_t)(NN+1)*4);
  int* cursor = (int*)carve((size_t)NN*4);
  int* cnt    = (int*)carve((size_t)NN*4);
  int* csrsrc = (int*)carve((size_t)NE*4);
  int* bsum   = (int*)carve(64*4);
  __bf16* pWhi = (__bf16*)carve((size_t)90112*2);
  __bf16* pWlo = (__bf16*)carve((size_t)90112*2);

  const int* esrc = ei;
  const int* edst = ei + NE;

  // one-time weight repack into MFMA fragment layout (bf16 hi/lo)
  repack_w<<<44, 256, 0, stream>>>(Wg, w1, w2, pWhi, pWlo);

  hipMemsetAsync(cnt, 0, (size_t)NN*4, stream);
  count_edges<<<(NE+255)/256, 256, 0, stream>>>(edst, cnt);
  scan1<<<49, 256, 0, stream>>>(cnt, offs, bsum);
  scan2<<<1, 64, 0, stream>>>(bsum);
  scan3<<<(NN+255)/256, 256, 0, stream>>>(offs, bsum, cursor);
  fill_csr<<<(NE+255)/256, 256, 0, stream>>>(esrc, edst, cursor, csrsrc);

  input_mlp<<<NN/8, 256, 0, stream>>>(x, w_in, b_in, ln_in_w, ln_in_b, h);

  const int GRID  = (NN + 63) / 64;   // 1563 (full-width waves)
  const int GRIDS = (NN + 31) / 32;   // 3125 (col-split waves)
  for (int i=0;i<4;i++){
    gemm_mfma<128,false,false,false,true,false,true,true><<<GRIDS, 256, 0, stream>>>(
        h, pWhi + (size_t)i*16384, pWlo + (size_t)i*16384, nullptr, nullptr, nullptr,
        a_src + i*128, a_dst + i*128, nullptr, xwb, als, ald, nullptr, nullptr, nullptr);
    gat_aggregate<<<NN/16, 256, 0, stream>>>(xwb, als, ald, offs, csrsrc,
        bg + i*128, lnw + i*128, lnb + i*128, h);
  }

  gemm_mfma<128,true,true,true,false,false,false,false><<<GRID, 256, 0, stream>>>(
      h, pWhi + 65536, pWlo + 65536, b1, lnow, lnob, nullptr, nullptr, xw, nullptr,
      nullptr, nullptr, nullptr, nullptr, nullptr);
  gemm_mfma<64,true,false,true,false,true,false,false><<<GRID, 256, 0, stream>>>(
      xw, pWhi + 81920, pWlo + 81920, b2, nullptr, nullptr, nullptr, nullptr, nullptr, nullptr,
      nullptr, nullptr, w3, b3, out);
}

// Round 25
// 411.376 us; speedup vs baseline: 1.2451x; 1.1357x over previous
//
#include <hip/hip_runtime.h>
#include <hip/hip_bf16.h>

#define NN 100000
#define NE 600000

typedef __bf16 bf16x8 __attribute__((ext_vector_type(8)));
typedef __bf16 bf16x4 __attribute__((ext_vector_type(4)));
typedef float  f32x4  __attribute__((ext_vector_type(4)));

__device__ __forceinline__ float dot4(float4 a, float4 b){
  return a.x*b.x + a.y*b.y + a.z*b.z + a.w*b.w;
}
// unpack 2 packed bf16 (low = even channel) to floats
__device__ __forceinline__ void bf2f(unsigned v, float& a, float& b){
  union { unsigned u; float f; } ua, ub;
  ua.u = v << 16;
  ub.u = v & 0xFFFF0000u;
  a = ua.f; b = ub.f;
}
__device__ __forceinline__ void bf8f(uint4 v, float* r){
  bf2f(v.x, r[0], r[1]);
  bf2f(v.y, r[2], r[3]);
  bf2f(v.z, r[4], r[5]);
  bf2f(v.w, r[6], r[7]);
}

// ---------------- CSR build (dst-grouped) ----------------
__global__ void count_edges(const int* __restrict__ dst, int* __restrict__ cnt){
  int e = blockIdx.x*256 + threadIdx.x;
  if (e < NE){
    unsigned d = (unsigned)dst[e];
    if (d < NN) atomicAdd(&cnt[d], 1);
  }
}

__global__ void scan1(const int* __restrict__ cnt, int* __restrict__ offs, int* __restrict__ bsum){
  __shared__ int sh[256];
  const int tid = threadIdx.x;
  const int base = blockIdx.x*2048 + tid*8;
  int pre[8]; int s = 0;
  #pragma unroll
  for (int j=0;j<8;j++){
    int idx = base + j;
    int v = (idx < NN) ? cnt[idx] : 0;
    pre[j] = s; s += v;
  }
  sh[tid] = s;
  __syncthreads();
  for (int d=1; d<256; d<<=1){
    int t = (tid >= d) ? sh[tid-d] : 0;
    __syncthreads();
    sh[tid] += t;
    __syncthreads();
  }
  int off = (tid > 0) ? sh[tid-1] : 0;
  #pragma unroll
  for (int j=0;j<8;j++){
    int idx = base + j;
    if (idx < NN) offs[idx] = off + pre[j];
  }
  if (tid == 255) bsum[blockIdx.x] = sh[255];
}

__global__ void scan2(int* __restrict__ bsum){
  if (threadIdx.x == 0){
    int s = 0;
    for (int i=0;i<49;i++){ int t = bsum[i]; bsum[i] = s; s += t; }
  }
}

__global__ void scan3(int* __restrict__ offs, const int* __restrict__ bsum, int* __restrict__ cursor){
  int i = blockIdx.x*256 + threadIdx.x;
  if (i < NN){
    int v = offs[i] + bsum[i>>11];
    offs[i] = v; cursor[i] = v;
  }
  if (i == 0) offs[NN] = NE;
}

__global__ void fill_csr(const int* __restrict__ src, const int* __restrict__ dst,
                         int* __restrict__ cursor, int* __restrict__ csrsrc){
  int e = blockIdx.x*256 + threadIdx.x;
  if (e < NE){
    unsigned d = (unsigned)dst[e];
    unsigned s = (unsigned)src[e];
    if (d < NN && s < NN){
      int p = atomicAdd(&cursor[d], 1);
      csrsrc[p] = (int)s;
    }
  }
}

// ---------------- weight repack: fp32 W[K][C] -> bf16 hi/lo MFMA fragments ----
__global__ void repack_w(const float* __restrict__ Wg, const float* __restrict__ w1,
                         const float* __restrict__ w2,
                         __bf16* __restrict__ phi, __bf16* __restrict__ plo)
{
  int gid = blockIdx.x*256 + threadIdx.x;
  const float* W; int C; size_t obase; int rem;
  if (gid < 8192)      { W = Wg + (size_t)(gid/2048)*16384; C = 128; obase = (size_t)(gid/2048)*16384; rem = gid % 2048; }
  else if (gid < 10240){ W = w1; C = 128; obase = 65536; rem = gid - 8192; }
  else if (gid < 11264){ W = w2; C = 64;  obase = 81920; rem = gid - 10240; }
  else return;
  const int lane = rem & 63;
  const int tks  = rem >> 6;
  const int ks = tks & 3, t = tks >> 2;
  const int col = t*16 + (lane & 15);
  const int kb  = ks*32 + (lane >> 4)*8;
  const size_t o = obase + (size_t)rem*8;
  #pragma unroll
  for (int j=0;j<8;j++){
    float v = W[(size_t)(kb+j)*C + col];
    __bf16 hb = (__bf16)v;
    phi[o+j] = hb;
    plo[o+j] = (__bf16)(v - (float)hb);
  }
}

// ---------------- input MLP: h = relu(LN(x@w_in+b_in)), h stored bf16 --------
__global__ __launch_bounds__(256) void input_mlp(const float* __restrict__ x,
    const float* __restrict__ win, const float* __restrict__ b,
    const float* __restrict__ lnw, const float* __restrict__ lnb,
    __bf16* __restrict__ h)
{
  const int tid = threadIdx.x;
  const int g = tid >> 5, l = tid & 31;
  const int n = blockIdx.x*8 + g;
  const float4* W4 = (const float4*)win;
  float xr[6];
  #pragma unroll
  for (int k=0;k<6;k++) xr[k] = x[n*6+k];
  float4 s = ((const float4*)b)[l];
  #pragma unroll
  for (int k=0;k<6;k++){
    float4 w = W4[k*32 + l];
    s.x = fmaf(xr[k], w.x, s.x);
    s.y = fmaf(xr[k], w.y, s.y);
    s.z = fmaf(xr[k], w.z, s.z);
    s.w = fmaf(xr[k], w.w, s.w);
  }
  float sum = s.x+s.y+s.z+s.w;
  float sq  = dot4(s,s);
  #pragma unroll
  for (int o=16;o>=1;o>>=1){ sum += __shfl_xor(sum,o); sq += __shfl_xor(sq,o); }
  float mean = sum*(1.f/128.f);
  float var  = sq*(1.f/128.f) - mean*mean;
  float rr = rsqrtf(var + 1e-5f);
  float4 lw = ((const float4*)lnw)[l];
  float4 lb = ((const float4*)lnb)[l];
  bf16x4 y;
  y[0] = (__bf16)fmaxf((s.x-mean)*rr*lw.x + lb.x, 0.f);
  y[1] = (__bf16)fmaxf((s.y-mean)*rr*lw.y + lb.y, 0.f);
  y[2] = (__bf16)fmaxf((s.z-mean)*rr*lw.z + lb.z, 0.f);
  y[3] = (__bf16)fmaxf((s.w-mean)*rr*lw.w + lb.w, 0.f);
  *(bf16x4*)(h + (size_t)n*128 + 4*l) = y;
}

// ---------------- MFMA split-bf16 GEMM: Y = act(LN?(X@W + b)), K=128 ----------
// ABF16: A operand loaded directly as bf16 (h is stored bf16) -> no hi/lo
//   split, A-read bytes halve. GAT also SKIPLO -> single MFMA term Ahi*Bhi.
//   o1: Ahi*(Bhi+Blo). o2 (fp32 xw input): full 3-MFMA split path.
// SPLIT (GAT only): each wave handles 16 rows x 64 cols (NT=4).
template<int C, bool HAS_BIAS, bool DO_LN, bool DO_RELU, bool GAT, bool OUTP, bool SPLIT, bool SKIPLO, bool ABF16>
__global__ __launch_bounds__(256) void gemm_mfma(
    const float* __restrict__ Xf, const __bf16* __restrict__ Xb,
    const __bf16* __restrict__ Bhi, const __bf16* __restrict__ Blo,
    const float* __restrict__ bias,
    const float* __restrict__ lnw, const float* __restrict__ lnb,
    const float* __restrict__ asrc, const float* __restrict__ adst,
    float* __restrict__ Y, __bf16* __restrict__ Yb,
    float* __restrict__ als, float* __restrict__ ald,
    const float* __restrict__ w3, const float* __restrict__ b3,
    float* __restrict__ outp)
{
  constexpr int NT = SPLIT ? C/32 : C/16;
  const int tid = threadIdx.x;
  const int wid = tid >> 6, lane = tid & 63;
  const int lrow = lane & 15, lgrp = lane >> 4;
  const int m0    = SPLIT ? (blockIdx.x*32 + (wid>>1)*16) : ((blockIdx.x*4 + wid)*16);
  const int colt0 = SPLIT ? (wid & 1)*NT : 0;   // starting 16-col tile index

  bf16x8 Ahi[4], Alo[4];
  {
    int row = m0 + lrow; if (row >= NN) row = NN-1;
    if constexpr (ABF16){
      const __bf16* Xr = Xb + (size_t)row*128 + lgrp*8;
      #pragma unroll
      for (int ks=0; ks<4; ks++) Ahi[ks] = *(const bf16x8*)(Xr + ks*32);
    } else {
      const float* Xr = Xf + (size_t)row*128 + lgrp*8;
      #pragma unroll
      for (int ks=0; ks<4; ks++){
        float4 u0 = *(const float4*)(Xr + ks*32);
        float4 u1 = *(const float4*)(Xr + ks*32 + 4);
        float v[8] = {u0.x,u0.y,u0.z,u0.w,u1.x,u1.y,u1.z,u1.w};
        bf16x8 h8, l8;
        #pragma unroll
        for (int j=0;j<8;j++){
          __bf16 hb = (__bf16)v[j];
          h8[j] = hb;
          l8[j] = (__bf16)(v[j] - (float)hb);
        }
        Ahi[ks] = h8; Alo[ks] = l8;
      }
    }
  }

  f32x4 acc[NT];
  #pragma unroll
  for (int t=0;t<NT;t++){ acc[t] = (f32x4){0.f,0.f,0.f,0.f}; }

  const bf16x8* B8h = (const bf16x8*)Bhi;
  const bf16x8* B8l = (const bf16x8*)Blo;
  #pragma unroll
  for (int ks=0;ks<4;ks++){
    bf16x8 bh[NT];
    #pragma unroll
    for (int t=0;t<NT;t++) bh[t] = B8h[((colt0+t)*4+ks)*64 + lane];
    #pragma unroll
    for (int t=0;t<NT;t++)
      acc[t] = __builtin_amdgcn_mfma_f32_16x16x32_bf16(Ahi[ks], bh[t], acc[t], 0,0,0);
    if constexpr (!ABF16){
      #pragma unroll
      for (int t=0;t<NT;t++)
        acc[t] = __builtin_amdgcn_mfma_f32_16x16x32_bf16(Alo[ks], bh[t], acc[t], 0,0,0);
    }
    if constexpr (!SKIPLO){
      #pragma unroll
      for (int t=0;t<NT;t++){
        bf16x8 bl = B8l[((colt0+t)*4+ks)*64 + lane];
        acc[t] = __builtin_amdgcn_mfma_f32_16x16x32_bf16(Ahi[ks], bl, acc[t], 0,0,0);
      }
    }
  }

  if constexpr (HAS_BIAS){
    #pragma unroll
    for (int t=0;t<NT;t++){
      float bv = bias[(colt0+t)*16 + lrow];
      #pragma unroll
      for (int i=0;i<4;i++) acc[t][i] += bv;
    }
  }

  if constexpr (GAT){
    #pragma unroll
    for (int t=0;t<NT;t++){
      float av = asrc[(colt0+t)*16 + lrow];
      float dv2 = adst[(colt0+t)*16 + lrow];
      float ps[4], pd[4];
      #pragma unroll
      for (int i=0;i<4;i++){
        int n = m0 + lgrp*4 + i;
        if (n < NN) Yb[(size_t)n*C + (colt0+t)*16 + lrow] = (__bf16)acc[t][i];
        ps[i] = acc[t][i]*av; pd[i] = acc[t][i]*dv2;
      }
      #pragma unroll
      for (int off=1; off<16; off<<=1){
        #pragma unroll
        for (int i=0;i<4;i++){
          ps[i] += __shfl_xor(ps[i], off);
          pd[i] += __shfl_xor(pd[i], off);
        }
      }
      if (lrow == 0){
        #pragma unroll
        for (int i=0;i<4;i++){
          int n = m0 + lgrp*4 + i;
          if (n < NN){ als[n*8 + colt0 + t] = ps[i]; ald[n*8 + colt0 + t] = pd[i]; }
        }
      }
    }
  } else {
    if constexpr (DO_LN){
      float s[4] = {0,0,0,0}, q[4] = {0,0,0,0};
      #pragma unroll
      for (int t=0;t<NT;t++){
        #pragma unroll
        for (int i=0;i<4;i++){ s[i] += acc[t][i]; q[i] += acc[t][i]*acc[t][i]; }
      }
      #pragma unroll
      for (int off=1; off<16; off<<=1){
        #pragma unroll
        for (int i=0;i<4;i++){ s[i] += __shfl_xor(s[i], off); q[i] += __shfl_xor(q[i], off); }
      }
      float mean[4], rr[4];
      #pragma unroll
      for (int i=0;i<4;i++){
        mean[i] = s[i]*(1.0f/C);
        float var = q[i]*(1.0f/C) - mean[i]*mean[i];
        rr[i] = rsqrtf(var + 1e-5f);
      }
      #pragma unroll
      for (int t=0;t<NT;t++){
        float lw = lnw[t*16 + lrow], lb = lnb[t*16 + lrow];
        #pragma unroll
        for (int i=0;i<4;i++){
          float v = (acc[t][i]-mean[i])*rr[i]*lw + lb;
          if constexpr (DO_RELU) v = fmaxf(v, 0.f);
          acc[t][i] = v;
        }
      }
    } else if constexpr (DO_RELU){
      #pragma unroll
      for (int t=0;t<NT;t++){
        #pragma unroll
        for (int i=0;i<4;i++) acc[t][i] = fmaxf(acc[t][i], 0.f);
      }
    }
    if constexpr (OUTP){
      float4 w3r[NT];
      #pragma unroll
      for (int t=0;t<NT;t++) w3r[t] = ((const float4*)w3)[t*16 + lrow];
      float4 b3v = *(const float4*)b3;
      #pragma unroll
      for (int i=0;i<4;i++){
        float4 po = make_float4(0.f,0.f,0.f,0.f);
        #pragma unroll
        for (int t=0;t<NT;t++){
          po.x = fmaf(acc[t][i], w3r[t].x, po.x);
          po.y = fmaf(acc[t][i], w3r[t].y, po.y);
          po.z = fmaf(acc[t][i], w3r[t].z, po.z);
          po.w = fmaf(acc[t][i], w3r[t].w, po.w);
        }
        #pragma unroll
        for (int off=1; off<16; off<<=1){
          po.x += __shfl_xor(po.x, off);
          po.y += __shfl_xor(po.y, off);
          po.z += __shfl_xor(po.z, off);
          po.w += __shfl_xor(po.w, off);
        }
        if (lrow == 0){
          int n = m0 + lgrp*4 + i;
          if (n < NN){
            float4 o;
            o.x = po.x + b3v.x; o.y = po.y + b3v.y;
            o.z = po.z + b3v.z; o.w = po.w + b3v.w;
            ((float4*)outp)[n] = o;
          }
        }
      }
    } else {
      #pragma unroll
      for (int t=0;t<NT;t++){
        #pragma unroll
        for (int i=0;i<4;i++){
          int n = m0 + lgrp*4 + i;
          if (n < NN) Y[(size_t)n*C + t*16 + lrow] = acc[t][i];
        }
      }
    }
  }
}

// ---------------- per-node softmax + aggregate + LN + residual ----------------
// FOUR nodes per wave: each 16-lane group owns ONE node (8 channels/lane via
// one uint4 bf16 load, head hh = sl>>1). h residual stream is bf16: one
// uint4 read + one uint4 write per lane (was 2x float4 each way).
__global__ __launch_bounds__(256) void gat_aggregate(
    const __bf16* __restrict__ xw, const float* __restrict__ als, const float* __restrict__ ald,
    const int* __restrict__ offs, const int* __restrict__ csrsrc,
    const float* __restrict__ bg, const float* __restrict__ lnw, const float* __restrict__ lnb,
    __bf16* __restrict__ h)
{
  const int tid = threadIdx.x;
  const int grp = tid >> 4, sl = tid & 15;
  const int n = blockIdx.x*16 + grp;
  const int hh = sl >> 1;                   // head of channels 8sl..8sl+7
  const float ad = ald[n*8 + hh];
  const uint4* xw128 = (const uint4*)xw;    // 8 bf16 per uint4; node row = 16 uint4

  // self-loop
  float t = als[n*8 + hh] + ad; t = t > 0.f ? t : 0.2f*t;
  float pp = __expf(t);
  float s = pp;
  float m[8];
  bf8f(xw128[(unsigned)n*16u + sl], m);
  float acc[8];
  #pragma unroll
  for (int c=0;c<8;c++) acc[c] = pp*m[c];

  const int start = offs[n], end = offs[n+1];
  int e = start;
  for (; e+4 <= end; e += 4){
    int s4[4]; float a[4]; uint4 x4[4];
    #pragma unroll
    for (int j=0;j<4;j++) s4[j] = csrsrc[e+j];
    #pragma unroll
    for (int j=0;j<4;j++){
      a[j]  = als[s4[j]*8 + hh];
      x4[j] = xw128[(unsigned)s4[j]*16u + sl];
    }
    #pragma unroll
    for (int j=0;j<4;j++){
      float u = a[j] + ad; u = u > 0.f ? u : 0.2f*u;
      float q = __expf(u);
      s += q;
      float mm[8];
      bf8f(x4[j], mm);
      #pragma unroll
      for (int c=0;c<8;c++) acc[c] = fmaf(q, mm[c], acc[c]);
    }
  }
  if (e+2 <= end){
    int sA = csrsrc[e], sB = csrsrc[e+1];
    float aA = als[sA*8+hh], aB = als[sB*8+hh];
    uint4 xA = xw128[(unsigned)sA*16u + sl];
    uint4 xB = xw128[(unsigned)sB*16u + sl];
    float u;
    u = aA+ad; u = u>0.f?u:0.2f*u; float qA = __expf(u);
    u = aB+ad; u = u>0.f?u:0.2f*u; float qB = __expf(u);
    s += qA+qB;
    float mA[8], mB[8];
    bf8f(xA, mA); bf8f(xB, mB);
    #pragma unroll
    for (int c=0;c<8;c++) acc[c] = fmaf(qA, mA[c], fmaf(qB, mB[c], acc[c]));
    e += 2;
  }
  if (e < end){
    int sA = csrsrc[e];
    float aA = als[sA*8+hh];
    uint4 xA = xw128[(unsigned)sA*16u + sl];
    float u = aA+ad; u = u>0.f?u:0.2f*u; float qA = __expf(u);
    s += qA;
    float mA[8];
    bf8f(xA, mA);
    #pragma unroll
    for (int c=0;c<8;c++) acc[c] = fmaf(qA, mA[c], acc[c]);
  }

  float4 bg0 = ((const float4*)bg)[2*sl];
  float4 bg1 = ((const float4*)bg)[2*sl+1];
  float bgv[8] = {bg0.x,bg0.y,bg0.z,bg0.w,bg1.x,bg1.y,bg1.z,bg1.w};
  float inv = 1.0f/s;
  float val[8];
  #pragma unroll
  for (int c=0;c<8;c++) val[c] = acc[c]*inv + bgv[c];
  // LayerNorm across 128 channels: butterfly over the 16 lanes of this group
  float sum = 0.f, sq = 0.f;
  #pragma unroll
  for (int c=0;c<8;c++){ sum += val[c]; sq += val[c]*val[c]; }
  #pragma unroll
  for (int off=8; off>=1; off>>=1){ sum += __shfl_xor(sum,off); sq += __shfl_xor(sq,off); }
  float mean = sum*(1.f/128.f);
  float var  = sq*(1.f/128.f) - mean*mean;
  float rr = rsqrtf(var + 1e-5f);
  float4 lw0 = ((const float4*)lnw)[2*sl];
  float4 lw1 = ((const float4*)lnw)[2*sl+1];
  float4 lb0 = ((const float4*)lnb)[2*sl];
  float4 lb1 = ((const float4*)lnb)[2*sl+1];
  float lwv[8] = {lw0.x,lw0.y,lw0.z,lw0.w,lw1.x,lw1.y,lw1.z,lw1.w};
  float lbv[8] = {lb0.x,lb0.y,lb0.z,lb0.w,lb1.x,lb1.y,lb1.z,lb1.w};
  bf16x8* hp = (bf16x8*)(h + (size_t)n*128 + 8*sl);
  bf16x8 hv8 = *hp;
  bf16x8 ho;
  #pragma unroll
  for (int c=0;c<8;c++){
    float hv = (float)hv8[c] + fmaxf((val[c]-mean)*rr*lwv[c] + lbv[c], 0.f);
    ho[c] = (__bf16)hv;
  }
  *hp = ho;
}

extern "C" void kernel_launch(void* const* d_in, const int* in_sizes, int n_in,
                              void* d_out, int out_size, void* d_ws, size_t ws_size,
                              hipStream_t stream)
{
  const float* x       = (const float*)d_in[0];
  const int*   ei      = (const int*)d_in[1];
  const float* w_in    = (const float*)d_in[2];
  const float* b_in    = (const float*)d_in[3];
  const float* ln_in_w = (const float*)d_in[4];
  const float* ln_in_b = (const float*)d_in[5];
  const float* Wg      = (const float*)d_in[6];
  const float* a_src   = (const float*)d_in[7];
  const float* a_dst   = (const float*)d_in[8];
  const float* bg      = (const float*)d_in[9];
  const float* lnw     = (const float*)d_in[10];
  const float* lnb     = (const float*)d_in[11];
  const float* w1      = (const float*)d_in[12];
  const float* b1      = (const float*)d_in[13];
  const float* lnow    = (const float*)d_in[14];
  const float* lnob    = (const float*)d_in[15];
  const float* w2      = (const float*)d_in[16];
  const float* b2      = (const float*)d_in[17];
  const float* w3      = (const float*)d_in[18];
  const float* b3      = (const float*)d_in[19];
  float* out = (float*)d_out;

  char* p = (char*)d_ws;
  auto carve = [&](size_t bytes)->void*{
    void* r = (void*)p; p += (bytes + 255) & ~(size_t)255; return r;
  };
  __bf16* h   = (__bf16*)carve((size_t)NN*128*2);  // bf16 residual stream
  float* xw   = (float*)carve((size_t)NN*128*4);   // fp32 o1 output
  __bf16* xwb = (__bf16*)carve((size_t)NN*128*2);  // bf16 GAT messages
  float* als  = (float*)carve((size_t)NN*8*4);
  float* ald  = (float*)carve((size_t)NN*8*4);
  int* offs   = (int*)carve((size_t)(NN+1)*4);
  int* cursor = (int*)carve((size_t)NN*4);
  int* cnt    = (int*)carve((size_t)NN*4);
  int* csrsrc = (int*)carve((size_t)NE*4);
  int* bsum   = (int*)carve(64*4);
  __bf16* pWhi = (__bf16*)carve((size_t)90112*2);
  __bf16* pWlo = (__bf16*)carve((size_t)90112*2);

  const int* esrc = ei;
  const int* edst = ei + NE;

  // one-time weight repack into MFMA fragment layout (bf16 hi/lo)
  repack_w<<<44, 256, 0, stream>>>(Wg, w1, w2, pWhi, pWlo);

  hipMemsetAsync(cnt, 0, (size_t)NN*4, stream);
  count_edges<<<(NE+255)/256, 256, 0, stream>>>(edst, cnt);
  scan1<<<49, 256, 0, stream>>>(cnt, offs, bsum);
  scan2<<<1, 64, 0, stream>>>(bsum);
  scan3<<<(NN+255)/256, 256, 0, stream>>>(offs, bsum, cursor);
  fill_csr<<<(NE+255)/256, 256, 0, stream>>>(esrc, edst, cursor, csrsrc);

  input_mlp<<<NN/8, 256, 0, stream>>>(x, w_in, b_in, ln_in_w, ln_in_b, h);

  const int GRID  = (NN + 63) / 64;   // 1563 (full-width waves)
  const int GRIDS = (NN + 31) / 32;   // 3125 (col-split waves)
  for (int i=0;i<4;i++){
    gemm_mfma<128,false,false,false,true,false,true,true,true><<<GRIDS, 256, 0, stream>>>(
        nullptr, h, pWhi + (size_t)i*16384, pWlo + (size_t)i*16384, nullptr, nullptr, nullptr,
        a_src + i*128, a_dst + i*128, nullptr, xwb, als, ald, nullptr, nullptr, nullptr);
    gat_aggregate<<<NN/16, 256, 0, stream>>>(xwb, als, ald, offs, csrsrc,
        bg + i*128, lnw + i*128, lnb + i*128, h);
  }

  gemm_mfma<128,true,true,true,false,false,false,false,true><<<GRID, 256, 0, stream>>>(
      nullptr, h, pWhi + 65536, pWlo + 65536, b1, lnow, lnob, nullptr, nullptr, xw, nullptr,
      nullptr, nullptr, nullptr, nullptr, nullptr);
  gemm_mfma<64,true,false,true,false,true,false,false,false><<<GRID, 256, 0, stream>>>(
      xw, nullptr, pWhi + 81920, pWlo + 81920, b2, nullptr, nullptr, nullptr, nullptr, nullptr, nullptr,
      nullptr, nullptr, w3, b3, out);
}

// Round 26
// 407.061 us; speedup vs baseline: 1.2583x; 1.0106x over previous
//
#include <hip/hip_runtime.h>
#include <hip/hip_bf16.h>

#define NN 100000
#define NE 600000

typedef __bf16 bf16x8 __attribute__((ext_vector_type(8)));
typedef __bf16 bf16x4 __attribute__((ext_vector_type(4)));
typedef float  f32x4  __attribute__((ext_vector_type(4)));
typedef float  f32x16 __attribute__((ext_vector_type(16)));

__device__ __forceinline__ float dot4(float4 a, float4 b){
  return a.x*b.x + a.y*b.y + a.z*b.z + a.w*b.w;
}
// unpack 2 packed bf16 (low = even channel) to floats
__device__ __forceinline__ void bf2f(unsigned v, float& a, float& b){
  union { unsigned u; float f; } ua, ub;
  ua.u = v << 16;
  ub.u = v & 0xFFFF0000u;
  a = ua.f; b = ub.f;
}
__device__ __forceinline__ void bf8f(uint4 v, float* r){
  bf2f(v.x, r[0], r[1]);
  bf2f(v.y, r[2], r[3]);
  bf2f(v.z, r[4], r[5]);
  bf2f(v.w, r[6], r[7]);
}

// ---------------- CSR build (dst-grouped) ----------------
__global__ void count_edges(const int* __restrict__ dst, int* __restrict__ cnt){
  int e = blockIdx.x*256 + threadIdx.x;
  if (e < NE){
    unsigned d = (unsigned)dst[e];
    if (d < NN) atomicAdd(&cnt[d], 1);
  }
}

__global__ void scan1(const int* __restrict__ cnt, int* __restrict__ offs, int* __restrict__ bsum){
  __shared__ int sh[256];
  const int tid = threadIdx.x;
  const int base = blockIdx.x*2048 + tid*8;
  int pre[8]; int s = 0;
  #pragma unroll
  for (int j=0;j<8;j++){
    int idx = base + j;
    int v = (idx < NN) ? cnt[idx] : 0;
    pre[j] = s; s += v;
  }
  sh[tid] = s;
  __syncthreads();
  for (int d=1; d<256; d<<=1){
    int t = (tid >= d) ? sh[tid-d] : 0;
    __syncthreads();
    sh[tid] += t;
    __syncthreads();
  }
  int off = (tid > 0) ? sh[tid-1] : 0;
  #pragma unroll
  for (int j=0;j<8;j++){
    int idx = base + j;
    if (idx < NN) offs[idx] = off + pre[j];
  }
  if (tid == 255) bsum[blockIdx.x] = sh[255];
}

__global__ void scan2(int* __restrict__ bsum){
  if (threadIdx.x == 0){
    int s = 0;
    for (int i=0;i<49;i++){ int t = bsum[i]; bsum[i] = s; s += t; }
  }
}

__global__ void scan3(int* __restrict__ offs, const int* __restrict__ bsum, int* __restrict__ cursor){
  int i = blockIdx.x*256 + threadIdx.x;
  if (i < NN){
    int v = offs[i] + bsum[i>>11];
    offs[i] = v; cursor[i] = v;
  }
  if (i == 0) offs[NN] = NE;
}

__global__ void fill_csr(const int* __restrict__ src, const int* __restrict__ dst,
                         int* __restrict__ cursor, int* __restrict__ csrsrc){
  int e = blockIdx.x*256 + threadIdx.x;
  if (e < NE){
    unsigned d = (unsigned)dst[e];
    unsigned s = (unsigned)src[e];
    if (d < NN && s < NN){
      int p = atomicAdd(&cursor[d], 1);
      csrsrc[p] = (int)s;
    }
  }
}

// ---------------- weight repack: fp32 W[K][C] -> bf16 hi/lo MFMA fragments ----
// 16x16x32 layout for o1/o2 (w1 @65536, w2 @81920; Wg part unused but harmless)
__global__ void repack_w(const float* __restrict__ Wg, const float* __restrict__ w1,
                         const float* __restrict__ w2,
                         __bf16* __restrict__ phi, __bf16* __restrict__ plo)
{
  int gid = blockIdx.x*256 + threadIdx.x;
  const float* W; int C; size_t obase; int rem;
  if (gid < 8192)      { W = Wg + (size_t)(gid/2048)*16384; C = 128; obase = (size_t)(gid/2048)*16384; rem = gid % 2048; }
  else if (gid < 10240){ W = w1; C = 128; obase = 65536; rem = gid - 8192; }
  else if (gid < 11264){ W = w2; C = 64;  obase = 81920; rem = gid - 10240; }
  else return;
  const int lane = rem & 63;
  const int tks  = rem >> 6;
  const int ks = tks & 3, t = tks >> 2;
  const int col = t*16 + (lane & 15);
  const int kb  = ks*32 + (lane >> 4)*8;
  const size_t o = obase + (size_t)rem*8;
  #pragma unroll
  for (int j=0;j<8;j++){
    float v = W[(size_t)(kb+j)*C + col];
    __bf16 hb = (__bf16)v;
    phi[o+j] = hb;
    plo[o+j] = (__bf16)(v - (float)hb);
  }
}

// 32x32x16 layout for GAT Wg + fused logit columns. Per layer: 5 tiles of 32
// cols. Tiles 0-3: Wg columns. Tile 4: cols 0-7 = va (Wg·a_src per head),
// cols 8-15 = vd (Wg·a_dst), cols 16-31 = 0. frag f=(t*8+ks)*64+lane, elem j:
// k = ks*16+(lane>>5)*8+j, col = t*32+(lane&31).
__global__ void repack_w32(const float* __restrict__ Wg,
                           const float* __restrict__ a_src, const float* __restrict__ a_dst,
                           __bf16* __restrict__ pb)
{
  int gid = blockIdx.x*256 + threadIdx.x;
  if (gid >= 10240) return;
  const int layer = gid / 2560, rem = gid % 2560;
  const float* W = Wg + (size_t)layer*16384;
  const int lane = rem & 63;
  const int tks  = rem >> 6;          // 0..39
  const int ks = tks & 7, t = tks >> 3;
  const int kb  = ks*16 + (lane >> 5)*8;
  const size_t o = (size_t)layer*20480 + (size_t)rem*8;
  if (t < 4){
    const int col = t*32 + (lane & 31);
    #pragma unroll
    for (int j=0;j<8;j++) pb[o+j] = (__bf16)W[(size_t)(kb+j)*128 + col];
  } else {
    const int cc = lane & 31;
    #pragma unroll
    for (int j=0;j<8;j++){
      float v = 0.f;
      if (cc < 16){
        const int hd = cc & 7;
        const float* av = (cc < 8 ? a_src : a_dst) + layer*128 + hd*16;
        const int k = kb + j;
        #pragma unroll
        for (int c=0;c<16;c++) v += W[(size_t)k*128 + hd*16 + c] * av[c];
      }
      pb[o+j] = (__bf16)v;
    }
  }
}

// ---------------- input MLP: h = relu(LN(x@w_in+b_in)), h stored bf16 --------
__global__ __launch_bounds__(256) void input_mlp(const float* __restrict__ x,
    const float* __restrict__ win, const float* __restrict__ b,
    const float* __restrict__ lnw, const float* __restrict__ lnb,
    __bf16* __restrict__ h)
{
  const int tid = threadIdx.x;
  const int g = tid >> 5, l = tid & 31;
  const int n = blockIdx.x*8 + g;
  const float4* W4 = (const float4*)win;
  float xr[6];
  #pragma unroll
  for (int k=0;k<6;k++) xr[k] = x[n*6+k];
  float4 s = ((const float4*)b)[l];
  #pragma unroll
  for (int k=0;k<6;k++){
    float4 w = W4[k*32 + l];
    s.x = fmaf(xr[k], w.x, s.x);
    s.y = fmaf(xr[k], w.y, s.y);
    s.z = fmaf(xr[k], w.z, s.z);
    s.w = fmaf(xr[k], w.w, s.w);
  }
  float sum = s.x+s.y+s.z+s.w;
  float sq  = dot4(s,s);
  #pragma unroll
  for (int o=16;o>=1;o>>=1){ sum += __shfl_xor(sum,o); sq += __shfl_xor(sq,o); }
  float mean = sum*(1.f/128.f);
  float var  = sq*(1.f/128.f) - mean*mean;
  float rr = rsqrtf(var + 1e-5f);
  float4 lw = ((const float4*)lnw)[l];
  float4 lb = ((const float4*)lnb)[l];
  bf16x4 y;
  y[0] = (__bf16)fmaxf((s.x-mean)*rr*lw.x + lb.x, 0.f);
  y[1] = (__bf16)fmaxf((s.y-mean)*rr*lw.y + lb.y, 0.f);
  y[2] = (__bf16)fmaxf((s.z-mean)*rr*lw.z + lb.z, 0.f);
  y[3] = (__bf16)fmaxf((s.w-mean)*rr*lw.w + lb.w, 0.f);
  *(bf16x4*)(h + (size_t)n*128 + 4*l) = y;
}

// ---------------- GAT GEMM, 32x32x16 MFMA, logits fused as B-tile 4 ----------
// One wave = 32 rows x 160 cols (4 Wg tiles + 1 logit tile). bf16 A direct
// (h is bf16), single MFMA term per tile. C/D layout (HW-verified):
// col=lane&31, row=(reg&3)+8*(reg>>2)+4*(lane>>5). Epilogue = pure stores:
// Yb from tiles 0-3; als/ald straight from tile-4 accumulators.
__global__ __launch_bounds__(256) void gemm32_gat(const __bf16* __restrict__ X,
    const __bf16* __restrict__ B32,
    __bf16* __restrict__ Yb, float* __restrict__ als, float* __restrict__ ald)
{
  const int tid = threadIdx.x;
  const int wid = tid >> 6, lane = tid & 63;
  const int lm = lane & 31, lh = lane >> 5;
  const int m0 = blockIdx.x*128 + wid*32;

  f32x16 acc[5];
  #pragma unroll
  for (int t=0;t<5;t++){
    #pragma unroll
    for (int i=0;i<16;i++) acc[t][i] = 0.f;
  }

  int row = m0 + lm; if (row >= NN) row = NN-1;
  const __bf16* Xr = X + (size_t)row*128 + lh*8;
  const bf16x8* B8 = (const bf16x8*)B32;

  #pragma unroll
  for (int ks=0; ks<8; ks++){
    bf16x8 a = *(const bf16x8*)(Xr + ks*16);
    bf16x8 bh[5];
    #pragma unroll
    for (int t=0;t<5;t++) bh[t] = B8[(t*8+ks)*64 + lane];
    #pragma unroll
    for (int t=0;t<5;t++)
      acc[t] = __builtin_amdgcn_mfma_f32_32x32x16_bf16(a, bh[t], acc[t], 0,0,0);
  }

  // Yb stores (per-register 64B coalesced runs)
  #pragma unroll
  for (int t=0;t<4;t++){
    #pragma unroll
    for (int i=0;i<16;i++){
      int r = (i&3) + 8*(i>>2) + 4*lh;
      int n = m0 + r;
      if (n < NN) Yb[(size_t)n*128 + t*32 + lm] = (__bf16)acc[t][i];
    }
  }
  // logits straight from accumulators: col 0-7 = als head, 8-15 = ald head
  #pragma unroll
  for (int i=0;i<16;i++){
    int r = (i&3) + 8*(i>>2) + 4*lh;
    int n = m0 + r;
    if (n < NN){
      if (lm < 8)       als[n*8 + lm]     = acc[4][i];
      else if (lm < 16) ald[n*8 + lm - 8] = acc[4][i];
    }
  }
}

// ---------------- MFMA split-bf16 GEMM (16x16x32): o1 (LN+ReLU) / o2 (+OUTP) --
template<int C, bool DO_LN, bool DO_RELU, bool OUTP, bool ABF16>
__global__ __launch_bounds__(256) void gemm_mfma(
    const float* __restrict__ Xf, const __bf16* __restrict__ Xb,
    const __bf16* __restrict__ Bhi, const __bf16* __restrict__ Blo,
    const float* __restrict__ bias,
    const float* __restrict__ lnw, const float* __restrict__ lnb,
    float* __restrict__ Y,
    const float* __restrict__ w3, const float* __restrict__ b3,
    float* __restrict__ outp)
{
  constexpr int NT = C/16;
  const int tid = threadIdx.x;
  const int wid = tid >> 6, lane = tid & 63;
  const int lrow = lane & 15, lgrp = lane >> 4;
  const int m0 = (blockIdx.x*4 + wid)*16;

  bf16x8 Ahi[4], Alo[4];
  {
    int row = m0 + lrow; if (row >= NN) row = NN-1;
    if constexpr (ABF16){
      const __bf16* Xr = Xb + (size_t)row*128 + lgrp*8;
      #pragma unroll
      for (int ks=0; ks<4; ks++) Ahi[ks] = *(const bf16x8*)(Xr + ks*32);
    } else {
      const float* Xr = Xf + (size_t)row*128 + lgrp*8;
      #pragma unroll
      for (int ks=0; ks<4; ks++){
        float4 u0 = *(const float4*)(Xr + ks*32);
        float4 u1 = *(const float4*)(Xr + ks*32 + 4);
        float v[8] = {u0.x,u0.y,u0.z,u0.w,u1.x,u1.y,u1.z,u1.w};
        bf16x8 h8, l8;
        #pragma unroll
        for (int j=0;j<8;j++){
          __bf16 hb = (__bf16)v[j];
          h8[j] = hb;
          l8[j] = (__bf16)(v[j] - (float)hb);
        }
        Ahi[ks] = h8; Alo[ks] = l8;
      }
    }
  }

  f32x4 acc[NT];
  #pragma unroll
  for (int t=0;t<NT;t++){ acc[t] = (f32x4){0.f,0.f,0.f,0.f}; }

  const bf16x8* B8h = (const bf16x8*)Bhi;
  const bf16x8* B8l = (const bf16x8*)Blo;
  #pragma unroll
  for (int ks=0;ks<4;ks++){
    bf16x8 bh[NT];
    #pragma unroll
    for (int t=0;t<NT;t++) bh[t] = B8h[(t*4+ks)*64 + lane];
    #pragma unroll
    for (int t=0;t<NT;t++)
      acc[t] = __builtin_amdgcn_mfma_f32_16x16x32_bf16(Ahi[ks], bh[t], acc[t], 0,0,0);
    if constexpr (!ABF16){
      #pragma unroll
      for (int t=0;t<NT;t++)
        acc[t] = __builtin_amdgcn_mfma_f32_16x16x32_bf16(Alo[ks], bh[t], acc[t], 0,0,0);
    }
    {
      #pragma unroll
      for (int t=0;t<NT;t++){
        bf16x8 bl = B8l[(t*4+ks)*64 + lane];
        acc[t] = __builtin_amdgcn_mfma_f32_16x16x32_bf16(Ahi[ks], bl, acc[t], 0,0,0);
      }
    }
  }

  #pragma unroll
  for (int t=0;t<NT;t++){
    float bv = bias[t*16 + lrow];
    #pragma unroll
    for (int i=0;i<4;i++) acc[t][i] += bv;
  }

  if constexpr (DO_LN){
    float s[4] = {0,0,0,0}, q[4] = {0,0,0,0};
    #pragma unroll
    for (int t=0;t<NT;t++){
      #pragma unroll
      for (int i=0;i<4;i++){ s[i] += acc[t][i]; q[i] += acc[t][i]*acc[t][i]; }
    }
    #pragma unroll
    for (int off=1; off<16; off<<=1){
      #pragma unroll
      for (int i=0;i<4;i++){ s[i] += __shfl_xor(s[i], off); q[i] += __shfl_xor(q[i], off); }
    }
    float mean[4], rr[4];
    #pragma unroll
    for (int i=0;i<4;i++){
      mean[i] = s[i]*(1.0f/C);
      float var = q[i]*(1.0f/C) - mean[i]*mean[i];
      rr[i] = rsqrtf(var + 1e-5f);
    }
    #pragma unroll
    for (int t=0;t<NT;t++){
      float lw = lnw[t*16 + lrow], lb = lnb[t*16 + lrow];
      #pragma unroll
      for (int i=0;i<4;i++){
        float v = (acc[t][i]-mean[i])*rr[i]*lw + lb;
        if constexpr (DO_RELU) v = fmaxf(v, 0.f);
        acc[t][i] = v;
      }
    }
  } else if constexpr (DO_RELU){
    #pragma unroll
    for (int t=0;t<NT;t++){
      #pragma unroll
      for (int i=0;i<4;i++) acc[t][i] = fmaxf(acc[t][i], 0.f);
    }
  }
  if constexpr (OUTP){
    float4 w3r[NT];
    #pragma unroll
    for (int t=0;t<NT;t++) w3r[t] = ((const float4*)w3)[t*16 + lrow];
    float4 b3v = *(const float4*)b3;
    #pragma unroll
    for (int i=0;i<4;i++){
      float4 po = make_float4(0.f,0.f,0.f,0.f);
      #pragma unroll
      for (int t=0;t<NT;t++){
        po.x = fmaf(acc[t][i], w3r[t].x, po.x);
        po.y = fmaf(acc[t][i], w3r[t].y, po.y);
        po.z = fmaf(acc[t][i], w3r[t].z, po.z);
        po.w = fmaf(acc[t][i], w3r[t].w, po.w);
      }
      #pragma unroll
      for (int off=1; off<16; off<<=1){
        po.x += __shfl_xor(po.x, off);
        po.y += __shfl_xor(po.y, off);
        po.z += __shfl_xor(po.z, off);
        po.w += __shfl_xor(po.w, off);
      }
      if (lrow == 0){
        int n = m0 + lgrp*4 + i;
        if (n < NN){
          float4 o;
          o.x = po.x + b3v.x; o.y = po.y + b3v.y;
          o.z = po.z + b3v.z; o.w = po.w + b3v.w;
          ((float4*)outp)[n] = o;
        }
      }
    }
  } else {
    #pragma unroll
    for (int t=0;t<NT;t++){
      #pragma unroll
      for (int i=0;i<4;i++){
        int n = m0 + lgrp*4 + i;
        if (n < NN) Y[(size_t)n*C + t*16 + lrow] = acc[t][i];
      }
    }
  }
}

// ---------------- per-node softmax + aggregate + LN + residual ----------------
// FOUR nodes per wave: each 16-lane group owns ONE node (8 channels/lane via
// one uint4 bf16 load, head hh = sl>>1). h residual stream is bf16.
__global__ __launch_bounds__(256) void gat_aggregate(
    const __bf16* __restrict__ xw, const float* __restrict__ als, const float* __restrict__ ald,
    const int* __restrict__ offs, const int* __restrict__ csrsrc,
    const float* __restrict__ bg, const float* __restrict__ lnw, const float* __restrict__ lnb,
    __bf16* __restrict__ h)
{
  const int tid = threadIdx.x;
  const int grp = tid >> 4, sl = tid & 15;
  const int n = blockIdx.x*16 + grp;
  const int hh = sl >> 1;                   // head of channels 8sl..8sl+7
  const float ad = ald[n*8 + hh];
  const uint4* xw128 = (const uint4*)xw;    // 8 bf16 per uint4; node row = 16 uint4

  // self-loop
  float t = als[n*8 + hh] + ad; t = t > 0.f ? t : 0.2f*t;
  float pp = __expf(t);
  float s = pp;
  float m[8];
  bf8f(xw128[(unsigned)n*16u + sl], m);
  float acc[8];
  #pragma unroll
  for (int c=0;c<8;c++) acc[c] = pp*m[c];

  const int start = offs[n], end = offs[n+1];
  int e = start;
  for (; e+4 <= end; e += 4){
    int s4[4]; float a[4]; uint4 x4[4];
    #pragma unroll
    for (int j=0;j<4;j++) s4[j] = csrsrc[e+j];
    #pragma unroll
    for (int j=0;j<4;j++){
      a[j]  = als[s4[j]*8 + hh];
      x4[j] = xw128[(unsigned)s4[j]*16u + sl];
    }
    #pragma unroll
    for (int j=0;j<4;j++){
      float u = a[j] + ad; u = u > 0.f ? u : 0.2f*u;
      float q = __expf(u);
      s += q;
      float mm[8];
      bf8f(x4[j], mm);
      #pragma unroll
      for (int c=0;c<8;c++) acc[c] = fmaf(q, mm[c], acc[c]);
    }
  }
  if (e+2 <= end){
    int sA = csrsrc[e], sB = csrsrc[e+1];
    float aA = als[sA*8+hh], aB = als[sB*8+hh];
    uint4 xA = xw128[(unsigned)sA*16u + sl];
    uint4 xB = xw128[(unsigned)sB*16u + sl];
    float u;
    u = aA+ad; u = u>0.f?u:0.2f*u; float qA = __expf(u);
    u = aB+ad; u = u>0.f?u:0.2f*u; float qB = __expf(u);
    s += qA+qB;
    float mA[8], mB[8];
    bf8f(xA, mA); bf8f(xB, mB);
    #pragma unroll
    for (int c=0;c<8;c++) acc[c] = fmaf(qA, mA[c], fmaf(qB, mB[c], acc[c]));
    e += 2;
  }
  if (e < end){
    int sA = csrsrc[e];
    float aA = als[sA*8+hh];
    uint4 xA = xw128[(unsigned)sA*16u + sl];
    float u = aA+ad; u = u>0.f?u:0.2f*u; float qA = __expf(u);
    s += qA;
    float mA[8];
    bf8f(xA, mA);
    #pragma unroll
    for (int c=0;c<8;c++) acc[c] = fmaf(qA, mA[c], acc[c]);
  }

  float4 bg0 = ((const float4*)bg)[2*sl];
  float4 bg1 = ((const float4*)bg)[2*sl+1];
  float bgv[8] = {bg0.x,bg0.y,bg0.z,bg0.w,bg1.x,bg1.y,bg1.z,bg1.w};
  float inv = 1.0f/s;
  float val[8];
  #pragma unroll
  for (int c=0;c<8;c++) val[c] = acc[c]*inv + bgv[c];
  // LayerNorm across 128 channels: butterfly over the 16 lanes of this group
  float sum = 0.f, sq = 0.f;
  #pragma unroll
  for (int c=0;c<8;c++){ sum += val[c]; sq += val[c]*val[c]; }
  #pragma unroll
  for (int off=8; off>=1; off>>=1){ sum += __shfl_xor(sum,off); sq += __shfl_xor(sq,off); }
  float mean = sum*(1.f/128.f);
  float var  = sq*(1.f/128.f) - mean*mean;
  float rr = rsqrtf(var + 1e-5f);
  float4 lw0 = ((const float4*)lnw)[2*sl];
  float4 lw1 = ((const float4*)lnw)[2*sl+1];
  float4 lb0 = ((const float4*)lnb)[2*sl];
  float4 lb1 = ((const float4*)lnb)[2*sl+1];
  float lwv[8] = {lw0.x,lw0.y,lw0.z,lw0.w,lw1.x,lw1.y,lw1.z,lw1.w};
  float lbv[8] = {lb0.x,lb0.y,lb0.z,lb0.w,lb1.x,lb1.y,lb1.z,lb1.w};
  bf16x8* hp = (bf16x8*)(h + (size_t)n*128 + 8*sl);
  bf16x8 hv8 = *hp;
  bf16x8 ho;
  #pragma unroll
  for (int c=0;c<8;c++){
    float hv = (float)hv8[c] + fmaxf((val[c]-mean)*rr*lwv[c] + lbv[c], 0.f);
    ho[c] = (__bf16)hv;
  }
  *hp = ho;
}

extern "C" void kernel_launch(void* const* d_in, const int* in_sizes, int n_in,
                              void* d_out, int out_size, void* d_ws, size_t ws_size,
                              hipStream_t stream)
{
  const float* x       = (const float*)d_in[0];
  const int*   ei      = (const int*)d_in[1];
  const float* w_in    = (const float*)d_in[2];
  const float* b_in    = (const float*)d_in[3];
  const float* ln_in_w = (const float*)d_in[4];
  const float* ln_in_b = (const float*)d_in[5];
  const float* Wg      = (const float*)d_in[6];
  const float* a_src   = (const float*)d_in[7];
  const float* a_dst   = (const float*)d_in[8];
  const float* bg      = (const float*)d_in[9];
  const float* lnw     = (const float*)d_in[10];
  const float* lnb     = (const float*)d_in[11];
  const float* w1      = (const float*)d_in[12];
  const float* b1      = (const float*)d_in[13];
  const float* lnow    = (const float*)d_in[14];
  const float* lnob    = (const float*)d_in[15];
  const float* w2      = (const float*)d_in[16];
  const float* b2      = (const float*)d_in[17];
  const float* w3      = (const float*)d_in[18];
  const float* b3      = (const float*)d_in[19];
  float* out = (float*)d_out;

  char* p = (char*)d_ws;
  auto carve = [&](size_t bytes)->void*{
    void* r = (void*)p; p += (bytes + 255) & ~(size_t)255; return r;
  };
  __bf16* h   = (__bf16*)carve((size_t)NN*128*2);  // bf16 residual stream
  float* xw   = (float*)carve((size_t)NN*128*4);   // fp32 o1 output
  __bf16* xwb = (__bf16*)carve((size_t)NN*128*2);  // bf16 GAT messages
  float* als  = (float*)carve((size_t)NN*8*4);
  float* ald  = (float*)carve((size_t)NN*8*4);
  int* offs   = (int*)carve((size_t)(NN+1)*4);
  int* cursor = (int*)carve((size_t)NN*4);
  int* cnt    = (int*)carve((size_t)NN*4);
  int* csrsrc = (int*)carve((size_t)NE*4);
  int* bsum   = (int*)carve(64*4);
  __bf16* pWhi = (__bf16*)carve((size_t)90112*2);
  __bf16* pWlo = (__bf16*)carve((size_t)90112*2);
  __bf16* pW32 = (__bf16*)carve((size_t)4*20480*2);  // 32x32 GAT frags + logit cols

  const int* esrc = ei;
  const int* edst = ei + NE;

  // one-time weight repacks
  repack_w<<<44, 256, 0, stream>>>(Wg, w1, w2, pWhi, pWlo);
  repack_w32<<<40, 256, 0, stream>>>(Wg, a_src, a_dst, pW32);

  hipMemsetAsync(cnt, 0, (size_t)NN*4, stream);
  count_edges<<<(NE+255)/256, 256, 0, stream>>>(edst, cnt);
  scan1<<<49, 256, 0, stream>>>(cnt, offs, bsum);
  scan2<<<1, 64, 0, stream>>>(bsum);
  scan3<<<(NN+255)/256, 256, 0, stream>>>(offs, bsum, cursor);
  fill_csr<<<(NE+255)/256, 256, 0, stream>>>(esrc, edst, cursor, csrsrc);

  input_mlp<<<NN/8, 256, 0, stream>>>(x, w_in, b_in, ln_in_w, ln_in_b, h);

  const int GRID   = (NN + 63) / 64;    // 1563 (16x16 full-width)
  const int GRID32 = (NN + 127) / 128;  // 782  (32x32 GAT: 128 rows/block)
  for (int i=0;i<4;i++){
    gemm32_gat<<<GRID32, 256, 0, stream>>>(
        h, pW32 + (size_t)i*20480, xwb, als, ald);
    gat_aggregate<<<NN/16, 256, 0, stream>>>(xwb, als, ald, offs, csrsrc,
        bg + i*128, lnw + i*128, lnb + i*128, h);
  }

  gemm_mfma<128,true,true,false,true><<<GRID, 256, 0, stream>>>(
      nullptr, h, pWhi + 65536, pWlo + 65536, b1, lnow, lnob, xw, nullptr, nullptr, nullptr);
  gemm_mfma<64,false,true,true,false><<<GRID, 256, 0, stream>>>(
      xw, nullptr, pWhi + 81920, pWlo + 81920, b2, nullptr, nullptr, nullptr, w3, b3, out);
}

// Round 27
// 401.468 us; speedup vs baseline: 1.2759x; 1.0139x over previous
//
#include <hip/hip_runtime.h>
#include <hip/hip_bf16.h>

#define NN 100000
#define NE 600000

typedef __bf16 bf16x8 __attribute__((ext_vector_type(8)));
typedef __bf16 bf16x4 __attribute__((ext_vector_type(4)));
typedef float  f32x4  __attribute__((ext_vector_type(4)));
typedef float  f32x16 __attribute__((ext_vector_type(16)));

__device__ __forceinline__ float dot4(float4 a, float4 b){
  return a.x*b.x + a.y*b.y + a.z*b.z + a.w*b.w;
}
// unpack 2 packed bf16 (low = even channel) to floats
__device__ __forceinline__ void bf2f(unsigned v, float& a, float& b){
  union { unsigned u; float f; } ua, ub;
  ua.u = v << 16;
  ub.u = v & 0xFFFF0000u;
  a = ua.f; b = ub.f;
}
__device__ __forceinline__ void bf8f(uint4 v, float* r){
  bf2f(v.x, r[0], r[1]);
  bf2f(v.y, r[2], r[3]);
  bf2f(v.z, r[4], r[5]);
  bf2f(v.w, r[6], r[7]);
}

// ---------------- CSR build (dst-grouped) ----------------
__global__ void count_edges(const int* __restrict__ dst, int* __restrict__ cnt){
  int e = blockIdx.x*256 + threadIdx.x;
  if (e < NE){
    unsigned d = (unsigned)dst[e];
    if (d < NN) atomicAdd(&cnt[d], 1);
  }
}

__global__ void scan1(const int* __restrict__ cnt, int* __restrict__ offs, int* __restrict__ bsum){
  __shared__ int sh[256];
  const int tid = threadIdx.x;
  const int base = blockIdx.x*2048 + tid*8;
  int pre[8]; int s = 0;
  #pragma unroll
  for (int j=0;j<8;j++){
    int idx = base + j;
    int v = (idx < NN) ? cnt[idx] : 0;
    pre[j] = s; s += v;
  }
  sh[tid] = s;
  __syncthreads();
  for (int d=1; d<256; d<<=1){
    int t = (tid >= d) ? sh[tid-d] : 0;
    __syncthreads();
    sh[tid] += t;
    __syncthreads();
  }
  int off = (tid > 0) ? sh[tid-1] : 0;
  #pragma unroll
  for (int j=0;j<8;j++){
    int idx = base + j;
    if (idx < NN) offs[idx] = off + pre[j];
  }
  if (tid == 255) bsum[blockIdx.x] = sh[255];
}

__global__ void scan2(int* __restrict__ bsum){
  if (threadIdx.x == 0){
    int s = 0;
    for (int i=0;i<49;i++){ int t = bsum[i]; bsum[i] = s; s += t; }
  }
}

__global__ void scan3(int* __restrict__ offs, const int* __restrict__ bsum, int* __restrict__ cursor){
  int i = blockIdx.x*256 + threadIdx.x;
  if (i < NN){
    int v = offs[i] + bsum[i>>11];
    offs[i] = v; cursor[i] = v;
  }
  if (i == 0) offs[NN] = NE;
}

__global__ void fill_csr(const int* __restrict__ src, const int* __restrict__ dst,
                         int* __restrict__ cursor, int* __restrict__ csrsrc){
  int e = blockIdx.x*256 + threadIdx.x;
  if (e < NE){
    unsigned d = (unsigned)dst[e];
    unsigned s = (unsigned)src[e];
    if (d < NN && s < NN){
      int p = atomicAdd(&cursor[d], 1);
      csrsrc[p] = (int)s;
    }
  }
}

// ---------------- weight repack: fp32 W[K][C] -> bf16 hi/lo MFMA fragments ----
// 16x16x32 layout for o1/o2 (w1 @65536, w2 @81920; Wg part unused but harmless)
__global__ void repack_w(const float* __restrict__ Wg, const float* __restrict__ w1,
                         const float* __restrict__ w2,
                         __bf16* __restrict__ phi, __bf16* __restrict__ plo)
{
  int gid = blockIdx.x*256 + threadIdx.x;
  const float* W; int C; size_t obase; int rem;
  if (gid < 8192)      { W = Wg + (size_t)(gid/2048)*16384; C = 128; obase = (size_t)(gid/2048)*16384; rem = gid % 2048; }
  else if (gid < 10240){ W = w1; C = 128; obase = 65536; rem = gid - 8192; }
  else if (gid < 11264){ W = w2; C = 64;  obase = 81920; rem = gid - 10240; }
  else return;
  const int lane = rem & 63;
  const int tks  = rem >> 6;
  const int ks = tks & 3, t = tks >> 2;
  const int col = t*16 + (lane & 15);
  const int kb  = ks*32 + (lane >> 4)*8;
  const size_t o = obase + (size_t)rem*8;
  #pragma unroll
  for (int j=0;j<8;j++){
    float v = W[(size_t)(kb+j)*C + col];
    __bf16 hb = (__bf16)v;
    phi[o+j] = hb;
    plo[o+j] = (__bf16)(v - (float)hb);
  }
}

// 32x32x16 layout for GAT Wg + fused logit columns. Per layer: 5 tiles of 32
// cols. Tiles 0-3: Wg columns. Tile 4: cols 0-7 = va (Wg·a_src per head),
// cols 8-15 = vd (Wg·a_dst), cols 16-31 = 0.
__global__ void repack_w32(const float* __restrict__ Wg,
                           const float* __restrict__ a_src, const float* __restrict__ a_dst,
                           __bf16* __restrict__ pb)
{
  int gid = blockIdx.x*256 + threadIdx.x;
  if (gid >= 10240) return;
  const int layer = gid / 2560, rem = gid % 2560;
  const float* W = Wg + (size_t)layer*16384;
  const int lane = rem & 63;
  const int tks  = rem >> 6;          // 0..39
  const int ks = tks & 7, t = tks >> 3;
  const int kb  = ks*16 + (lane >> 5)*8;
  const size_t o = (size_t)layer*20480 + (size_t)rem*8;
  if (t < 4){
    const int col = t*32 + (lane & 31);
    #pragma unroll
    for (int j=0;j<8;j++) pb[o+j] = (__bf16)W[(size_t)(kb+j)*128 + col];
  } else {
    const int cc = lane & 31;
    #pragma unroll
    for (int j=0;j<8;j++){
      float v = 0.f;
      if (cc < 16){
        const int hd = cc & 7;
        const float* av = (cc < 8 ? a_src : a_dst) + layer*128 + hd*16;
        const int k = kb + j;
        #pragma unroll
        for (int c=0;c<16;c++) v += W[(size_t)k*128 + hd*16 + c] * av[c];
      }
      pb[o+j] = (__bf16)v;
    }
  }
}

// ---------------- input MLP: h = relu(LN(x@w_in+b_in)), h stored bf16 --------
__global__ __launch_bounds__(256) void input_mlp(const float* __restrict__ x,
    const float* __restrict__ win, const float* __restrict__ b,
    const float* __restrict__ lnw, const float* __restrict__ lnb,
    __bf16* __restrict__ h)
{
  const int tid = threadIdx.x;
  const int g = tid >> 5, l = tid & 31;
  const int n = blockIdx.x*8 + g;
  const float4* W4 = (const float4*)win;
  float xr[6];
  #pragma unroll
  for (int k=0;k<6;k++) xr[k] = x[n*6+k];
  float4 s = ((const float4*)b)[l];
  #pragma unroll
  for (int k=0;k<6;k++){
    float4 w = W4[k*32 + l];
    s.x = fmaf(xr[k], w.x, s.x);
    s.y = fmaf(xr[k], w.y, s.y);
    s.z = fmaf(xr[k], w.z, s.z);
    s.w = fmaf(xr[k], w.w, s.w);
  }
  float sum = s.x+s.y+s.z+s.w;
  float sq  = dot4(s,s);
  #pragma unroll
  for (int o=16;o>=1;o>>=1){ sum += __shfl_xor(sum,o); sq += __shfl_xor(sq,o); }
  float mean = sum*(1.f/128.f);
  float var  = sq*(1.f/128.f) - mean*mean;
  float rr = rsqrtf(var + 1e-5f);
  float4 lw = ((const float4*)lnw)[l];
  float4 lb = ((const float4*)lnb)[l];
  bf16x4 y;
  y[0] = (__bf16)fmaxf((s.x-mean)*rr*lw.x + lb.x, 0.f);
  y[1] = (__bf16)fmaxf((s.y-mean)*rr*lw.y + lb.y, 0.f);
  y[2] = (__bf16)fmaxf((s.z-mean)*rr*lw.z + lb.z, 0.f);
  y[3] = (__bf16)fmaxf((s.w-mean)*rr*lw.w + lb.w, 0.f);
  *(bf16x4*)(h + (size_t)n*128 + 4*l) = y;
}

// ---------------- GAT GEMM, 32x32x16 MFMA, logits fused as B-tile 4 ----------
__global__ __launch_bounds__(256) void gemm32_gat(const __bf16* __restrict__ X,
    const __bf16* __restrict__ B32,
    __bf16* __restrict__ Yb, float* __restrict__ als, float* __restrict__ ald)
{
  const int tid = threadIdx.x;
  const int wid = tid >> 6, lane = tid & 63;
  const int lm = lane & 31, lh = lane >> 5;
  const int m0 = blockIdx.x*128 + wid*32;

  f32x16 acc[5];
  #pragma unroll
  for (int t=0;t<5;t++){
    #pragma unroll
    for (int i=0;i<16;i++) acc[t][i] = 0.f;
  }

  int row = m0 + lm; if (row >= NN) row = NN-1;
  const __bf16* Xr = X + (size_t)row*128 + lh*8;
  const bf16x8* B8 = (const bf16x8*)B32;

  #pragma unroll
  for (int ks=0; ks<8; ks++){
    bf16x8 a = *(const bf16x8*)(Xr + ks*16);
    bf16x8 bh[5];
    #pragma unroll
    for (int t=0;t<5;t++) bh[t] = B8[(t*8+ks)*64 + lane];
    #pragma unroll
    for (int t=0;t<5;t++)
      acc[t] = __builtin_amdgcn_mfma_f32_32x32x16_bf16(a, bh[t], acc[t], 0,0,0);
  }

  #pragma unroll
  for (int t=0;t<4;t++){
    #pragma unroll
    for (int i=0;i<16;i++){
      int r = (i&3) + 8*(i>>2) + 4*lh;
      int n = m0 + r;
      if (n < NN) Yb[(size_t)n*128 + t*32 + lm] = (__bf16)acc[t][i];
    }
  }
  #pragma unroll
  for (int i=0;i<16;i++){
    int r = (i&3) + 8*(i>>2) + 4*lh;
    int n = m0 + r;
    if (n < NN){
      if (lm < 8)       als[n*8 + lm]     = acc[4][i];
      else if (lm < 16) ald[n*8 + lm - 8] = acc[4][i];
    }
  }
}

// ---------------- MFMA split-bf16 GEMM (16x16x32): o1 (LN+ReLU) / o2 (+OUTP) --
// ABF16: A read directly as bf16 (no hi/lo split). YB16: store output bf16.
template<int C, bool DO_LN, bool DO_RELU, bool OUTP, bool ABF16, bool YB16>
__global__ __launch_bounds__(256) void gemm_mfma(
    const float* __restrict__ Xf, const __bf16* __restrict__ Xb,
    const __bf16* __restrict__ Bhi, const __bf16* __restrict__ Blo,
    const float* __restrict__ bias,
    const float* __restrict__ lnw, const float* __restrict__ lnb,
    float* __restrict__ Y, __bf16* __restrict__ Yb,
    const float* __restrict__ w3, const float* __restrict__ b3,
    float* __restrict__ outp)
{
  constexpr int NT = C/16;
  const int tid = threadIdx.x;
  const int wid = tid >> 6, lane = tid & 63;
  const int lrow = lane & 15, lgrp = lane >> 4;
  const int m0 = (blockIdx.x*4 + wid)*16;

  bf16x8 Ahi[4], Alo[4];
  {
    int row = m0 + lrow; if (row >= NN) row = NN-1;
    if constexpr (ABF16){
      const __bf16* Xr = Xb + (size_t)row*128 + lgrp*8;
      #pragma unroll
      for (int ks=0; ks<4; ks++) Ahi[ks] = *(const bf16x8*)(Xr + ks*32);
    } else {
      const float* Xr = Xf + (size_t)row*128 + lgrp*8;
      #pragma unroll
      for (int ks=0; ks<4; ks++){
        float4 u0 = *(const float4*)(Xr + ks*32);
        float4 u1 = *(const float4*)(Xr + ks*32 + 4);
        float v[8] = {u0.x,u0.y,u0.z,u0.w,u1.x,u1.y,u1.z,u1.w};
        bf16x8 h8, l8;
        #pragma unroll
        for (int j=0;j<8;j++){
          __bf16 hb = (__bf16)v[j];
          h8[j] = hb;
          l8[j] = (__bf16)(v[j] - (float)hb);
        }
        Ahi[ks] = h8; Alo[ks] = l8;
      }
    }
  }

  f32x4 acc[NT];
  #pragma unroll
  for (int t=0;t<NT;t++){ acc[t] = (f32x4){0.f,0.f,0.f,0.f}; }

  const bf16x8* B8h = (const bf16x8*)Bhi;
  const bf16x8* B8l = (const bf16x8*)Blo;
  #pragma unroll
  for (int ks=0;ks<4;ks++){
    bf16x8 bh[NT];
    #pragma unroll
    for (int t=0;t<NT;t++) bh[t] = B8h[(t*4+ks)*64 + lane];
    #pragma unroll
    for (int t=0;t<NT;t++)
      acc[t] = __builtin_amdgcn_mfma_f32_16x16x32_bf16(Ahi[ks], bh[t], acc[t], 0,0,0);
    if constexpr (!ABF16){
      #pragma unroll
      for (int t=0;t<NT;t++)
        acc[t] = __builtin_amdgcn_mfma_f32_16x16x32_bf16(Alo[ks], bh[t], acc[t], 0,0,0);
    }
    {
      #pragma unroll
      for (int t=0;t<NT;t++){
        bf16x8 bl = B8l[(t*4+ks)*64 + lane];
        acc[t] = __builtin_amdgcn_mfma_f32_16x16x32_bf16(Ahi[ks], bl, acc[t], 0,0,0);
      }
    }
  }

  #pragma unroll
  for (int t=0;t<NT;t++){
    float bv = bias[t*16 + lrow];
    #pragma unroll
    for (int i=0;i<4;i++) acc[t][i] += bv;
  }

  if constexpr (DO_LN){
    float s[4] = {0,0,0,0}, q[4] = {0,0,0,0};
    #pragma unroll
    for (int t=0;t<NT;t++){
      #pragma unroll
      for (int i=0;i<4;i++){ s[i] += acc[t][i]; q[i] += acc[t][i]*acc[t][i]; }
    }
    #pragma unroll
    for (int off=1; off<16; off<<=1){
      #pragma unroll
      for (int i=0;i<4;i++){ s[i] += __shfl_xor(s[i], off); q[i] += __shfl_xor(q[i], off); }
    }
    float mean[4], rr[4];
    #pragma unroll
    for (int i=0;i<4;i++){
      mean[i] = s[i]*(1.0f/C);
      float var = q[i]*(1.0f/C) - mean[i]*mean[i];
      rr[i] = rsqrtf(var + 1e-5f);
    }
    #pragma unroll
    for (int t=0;t<NT;t++){
      float lw = lnw[t*16 + lrow], lb = lnb[t*16 + lrow];
      #pragma unroll
      for (int i=0;i<4;i++){
        float v = (acc[t][i]-mean[i])*rr[i]*lw + lb;
        if constexpr (DO_RELU) v = fmaxf(v, 0.f);
        acc[t][i] = v;
      }
    }
  } else if constexpr (DO_RELU){
    #pragma unroll
    for (int t=0;t<NT;t++){
      #pragma unroll
      for (int i=0;i<4;i++) acc[t][i] = fmaxf(acc[t][i], 0.f);
    }
  }
  if constexpr (OUTP){
    float4 w3r[NT];
    #pragma unroll
    for (int t=0;t<NT;t++) w3r[t] = ((const float4*)w3)[t*16 + lrow];
    float4 b3v = *(const float4*)b3;
    #pragma unroll
    for (int i=0;i<4;i++){
      float4 po = make_float4(0.f,0.f,0.f,0.f);
      #pragma unroll
      for (int t=0;t<NT;t++){
        po.x = fmaf(acc[t][i], w3r[t].x, po.x);
        po.y = fmaf(acc[t][i], w3r[t].y, po.y);
        po.z = fmaf(acc[t][i], w3r[t].z, po.z);
        po.w = fmaf(acc[t][i], w3r[t].w, po.w);
      }
      #pragma unroll
      for (int off=1; off<16; off<<=1){
        po.x += __shfl_xor(po.x, off);
        po.y += __shfl_xor(po.y, off);
        po.z += __shfl_xor(po.z, off);
        po.w += __shfl_xor(po.w, off);
      }
      if (lrow == 0){
        int n = m0 + lgrp*4 + i;
        if (n < NN){
          float4 o;
          o.x = po.x + b3v.x; o.y = po.y + b3v.y;
          o.z = po.z + b3v.z; o.w = po.w + b3v.w;
          ((float4*)outp)[n] = o;
        }
      }
    }
  } else {
    #pragma unroll
    for (int t=0;t<NT;t++){
      #pragma unroll
      for (int i=0;i<4;i++){
        int n = m0 + lgrp*4 + i;
        if (n < NN){
          if constexpr (YB16) Yb[(size_t)n*C + t*16 + lrow] = (__bf16)acc[t][i];
          else                Y[(size_t)n*C + t*16 + lrow] = acc[t][i];
        }
      }
    }
  }
}

// ---------------- per-node softmax + aggregate + LN + residual ----------------
__global__ __launch_bounds__(256) void gat_aggregate(
    const __bf16* __restrict__ xw, const float* __restrict__ als, const float* __restrict__ ald,
    const int* __restrict__ offs, const int* __restrict__ csrsrc,
    const float* __restrict__ bg, const float* __restrict__ lnw, const float* __restrict__ lnb,
    __bf16* __restrict__ h)
{
  const int tid = threadIdx.x;
  const int grp = tid >> 4, sl = tid & 15;
  const int n = blockIdx.x*16 + grp;
  const int hh = sl >> 1;                   // head of channels 8sl..8sl+7
  const float ad = ald[n*8 + hh];
  const uint4* xw128 = (const uint4*)xw;    // 8 bf16 per uint4; node row = 16 uint4

  // self-loop
  float t = als[n*8 + hh] + ad; t = t > 0.f ? t : 0.2f*t;
  float pp = __expf(t);
  float s = pp;
  float m[8];
  bf8f(xw128[(unsigned)n*16u + sl], m);
  float acc[8];
  #pragma unroll
  for (int c=0;c<8;c++) acc[c] = pp*m[c];

  const int start = offs[n], end = offs[n+1];
  int e = start;
  for (; e+4 <= end; e += 4){
    int s4[4]; float a[4]; uint4 x4[4];
    #pragma unroll
    for (int j=0;j<4;j++) s4[j] = csrsrc[e+j];
    #pragma unroll
    for (int j=0;j<4;j++){
      a[j]  = als[s4[j]*8 + hh];
      x4[j] = xw128[(unsigned)s4[j]*16u + sl];
    }
    #pragma unroll
    for (int j=0;j<4;j++){
      float u = a[j] + ad; u = u > 0.f ? u : 0.2f*u;
      float q = __expf(u);
      s += q;
      float mm[8];
      bf8f(x4[j], mm);
      #pragma unroll
      for (int c=0;c<8;c++) acc[c] = fmaf(q, mm[c], acc[c]);
    }
  }
  if (e+2 <= end){
    int sA = csrsrc[e], sB = csrsrc[e+1];
    float aA = als[sA*8+hh], aB = als[sB*8+hh];
    uint4 xA = xw128[(unsigned)sA*16u + sl];
    uint4 xB = xw128[(unsigned)sB*16u + sl];
    float u;
    u = aA+ad; u = u>0.f?u:0.2f*u; float qA = __expf(u);
    u = aB+ad; u = u>0.f?u:0.2f*u; float qB = __expf(u);
    s += qA+qB;
    float mA[8], mB[8];
    bf8f(xA, mA); bf8f(xB, mB);
    #pragma unroll
    for (int c=0;c<8;c++) acc[c] = fmaf(qA, mA[c], fmaf(qB, mB[c], acc[c]));
    e += 2;
  }
  if (e < end){
    int sA = csrsrc[e];
    float aA = als[sA*8+hh];
    uint4 xA = xw128[(unsigned)sA*16u + sl];
    float u = aA+ad; u = u>0.f?u:0.2f*u; float qA = __expf(u);
    s += qA;
    float mA[8];
    bf8f(xA, mA);
    #pragma unroll
    for (int c=0;c<8;c++) acc[c] = fmaf(qA, mA[c], acc[c]);
  }

  float4 bg0 = ((const float4*)bg)[2*sl];
  float4 bg1 = ((const float4*)bg)[2*sl+1];
  float bgv[8] = {bg0.x,bg0.y,bg0.z,bg0.w,bg1.x,bg1.y,bg1.z,bg1.w};
  float inv = 1.0f/s;
  float val[8];
  #pragma unroll
  for (int c=0;c<8;c++) val[c] = acc[c]*inv + bgv[c];
  float sum = 0.f, sq = 0.f;
  #pragma unroll
  for (int c=0;c<8;c++){ sum += val[c]; sq += val[c]*val[c]; }
  #pragma unroll
  for (int off=8; off>=1; off>>=1){ sum += __shfl_xor(sum,off); sq += __shfl_xor(sq,off); }
  float mean = sum*(1.f/128.f);
  float var  = sq*(1.f/128.f) - mean*mean;
  float rr = rsqrtf(var + 1e-5f);
  float4 lw0 = ((const float4*)lnw)[2*sl];
  float4 lw1 = ((const float4*)lnw)[2*sl+1];
  float4 lb0 = ((const float4*)lnb)[2*sl];
  float4 lb1 = ((const float4*)lnb)[2*sl+1];
  float lwv[8] = {lw0.x,lw0.y,lw0.z,lw0.w,lw1.x,lw1.y,lw1.z,lw1.w};
  float lbv[8] = {lb0.x,lb0.y,lb0.z,lb0.w,lb1.x,lb1.y,lb1.z,lb1.w};
  bf16x8* hp = (bf16x8*)(h + (size_t)n*128 + 8*sl);
  bf16x8 hv8 = *hp;
  bf16x8 ho;
  #pragma unroll
  for (int c=0;c<8;c++){
    float hv = (float)hv8[c] + fmaxf((val[c]-mean)*rr*lwv[c] + lbv[c], 0.f);
    ho[c] = (__bf16)hv;
  }
  *hp = ho;
}

extern "C" void kernel_launch(void* const* d_in, const int* in_sizes, int n_in,
                              void* d_out, int out_size, void* d_ws, size_t ws_size,
                              hipStream_t stream)
{
  const float* x       = (const float*)d_in[0];
  const int*   ei      = (const int*)d_in[1];
  const float* w_in    = (const float*)d_in[2];
  const float* b_in    = (const float*)d_in[3];
  const float* ln_in_w = (const float*)d_in[4];
  const float* ln_in_b = (const float*)d_in[5];
  const float* Wg      = (const float*)d_in[6];
  const float* a_src   = (const float*)d_in[7];
  const float* a_dst   = (const float*)d_in[8];
  const float* bg      = (const float*)d_in[9];
  const float* lnw     = (const float*)d_in[10];
  const float* lnb     = (const float*)d_in[11];
  const float* w1      = (const float*)d_in[12];
  const float* b1      = (const float*)d_in[13];
  const float* lnow    = (const float*)d_in[14];
  const float* lnob    = (const float*)d_in[15];
  const float* w2      = (const float*)d_in[16];
  const float* b2      = (const float*)d_in[17];
  const float* w3      = (const float*)d_in[18];
  const float* b3      = (const float*)d_in[19];
  float* out = (float*)d_out;

  char* p = (char*)d_ws;
  auto carve = [&](size_t bytes)->void*{
    void* r = (void*)p; p += (bytes + 255) & ~(size_t)255; return r;
  };
  __bf16* h   = (__bf16*)carve((size_t)NN*128*2);  // bf16 residual stream
  __bf16* xwb = (__bf16*)carve((size_t)NN*128*2);  // bf16 GAT messages / o1 output
  float* als  = (float*)carve((size_t)NN*8*4);
  float* ald  = (float*)carve((size_t)NN*8*4);
  int* offs   = (int*)carve((size_t)(NN+1)*4);
  int* cursor = (int*)carve((size_t)NN*4);
  int* cnt    = (int*)carve((size_t)NN*4);
  int* csrsrc = (int*)carve((size_t)NE*4);
  int* bsum   = (int*)carve(64*4);
  __bf16* pWhi = (__bf16*)carve((size_t)90112*2);
  __bf16* pWlo = (__bf16*)carve((size_t)90112*2);
  __bf16* pW32 = (__bf16*)carve((size_t)4*20480*2);  // 32x32 GAT frags + logit cols

  const int* esrc = ei;
  const int* edst = ei + NE;

  // one-time weight repacks
  repack_w<<<44, 256, 0, stream>>>(Wg, w1, w2, pWhi, pWlo);
  repack_w32<<<40, 256, 0, stream>>>(Wg, a_src, a_dst, pW32);

  hipMemsetAsync(cnt, 0, (size_t)NN*4, stream);
  count_edges<<<(NE+255)/256, 256, 0, stream>>>(edst, cnt);
  scan1<<<49, 256, 0, stream>>>(cnt, offs, bsum);
  scan2<<<1, 64, 0, stream>>>(bsum);
  scan3<<<(NN+255)/256, 256, 0, stream>>>(offs, bsum, cursor);
  fill_csr<<<(NE+255)/256, 256, 0, stream>>>(esrc, edst, cursor, csrsrc);

  input_mlp<<<NN/8, 256, 0, stream>>>(x, w_in, b_in, ln_in_w, ln_in_b, h);

  const int GRID   = (NN + 63) / 64;    // 1563 (16x16 full-width)
  const int GRID32 = (NN + 127) / 128;  // 782  (32x32 GAT: 128 rows/block)
  for (int i=0;i<4;i++){
    gemm32_gat<<<GRID32, 256, 0, stream>>>(
        h, pW32 + (size_t)i*20480, xwb, als, ald);
    gat_aggregate<<<NN/16, 256, 0, stream>>>(xwb, als, ald, offs, csrsrc,
        bg + i*128, lnw + i*128, lnb + i*128, h);
  }

  // o1: h(bf16) @ w1 -> LN+ReLU -> xwb (bf16, reuses dead GAT-message buffer)
  gemm_mfma<128,true,true,false,true,true><<<GRID, 256, 0, stream>>>(
      nullptr, h, pWhi + 65536, pWlo + 65536, b1, lnow, lnob, nullptr, xwb,
      nullptr, nullptr, nullptr);
  // o2: xwb(bf16) @ w2 -> ReLU -> @w3+b3 fused -> out
  gemm_mfma<64,false,true,true,true,false><<<GRID, 256, 0, stream>>>(
      nullptr, xwb, pWhi + 81920, pWlo + 81920, b2, nullptr, nullptr, nullptr, nullptr,
      w3, b3, out);
}